// Round 8
// baseline (671.798 us; speedup 1.0000x reference)
//
#include <hip/hip_runtime.h>
#include <hip/hip_bf16.h>
#include <math.h>

#define ND 128
#define NH 8
#define DKK 16
#define NT 3
#define NR 4
#define NB 8
#define NMAT 10   // packed mats: 0=Q, 1..4=Kcomb[r], 5=V(type1), 6..9=Vcomb[r]

typedef unsigned short ushort_t;
typedef __bf16 bf16_t;
typedef bf16_t bf16x8 __attribute__((ext_vector_type(8)));
typedef float f32x4 __attribute__((ext_vector_type(4)));

__device__ __forceinline__ float bf2f(unsigned short u) {
    union { unsigned int i; float f; } v; v.i = ((unsigned int)u) << 16; return v.f;
}
__device__ __forceinline__ unsigned short f2bf(float f) {
    union { float f; unsigned int i; } v; v.f = f;
    unsigned int x = v.i;
    unsigned int lsb = (x >> 16) & 1u;
    x += 0x7fffu + lsb;
    return (unsigned short)(x >> 16);
}
__device__ __forceinline__ unsigned int pk2(float a, float b) {
    return (unsigned int)f2bf(a) | ((unsigned int)f2bf(b) << 16);
}
__device__ __forceinline__ void load_bf8(const ushort_t* p, float* o) {
    uint4 u = *reinterpret_cast<const uint4*>(p);
    o[0]=bf2f(u.x & 0xffff); o[1]=bf2f(u.x >> 16);
    o[2]=bf2f(u.y & 0xffff); o[3]=bf2f(u.y >> 16);
    o[4]=bf2f(u.z & 0xffff); o[5]=bf2f(u.z >> 16);
    o[6]=bf2f(u.w & 0xffff); o[7]=bf2f(u.w >> 16);
}
__device__ __forceinline__ bf16x8 as_bf16x8(uint4 u) {
    union { uint4 u; bf16x8 v; } c; c.u = u; return c.v;
}

// ---------------- sort / bucket infrastructure ----------------

__global__ void k_zero(int n, int* offs, int* winner, int* tcnt) {
    int i = blockIdx.x * 256 + threadIdx.x;
    if (i < n) { offs[i] = 0; winner[i] = -1; }
    if (i < NT) tcnt[i] = 0;
}

// wave-aggregated 3-bin atomics
__global__ void k_count(int n, int e, const int* src, const int* tgt, const int* etype,
                        const int* ntype, int* offs, int* winner, int* tcnt) {
    int i = blockIdx.x * 256 + threadIdx.x;
    if (i < e) {
        atomicAdd(&offs[tgt[i]], 1);
        if (etype[i] == 0) atomicMax(&winner[src[i]], i);  // numpy last-write-wins == max edge id
    }
    if (i < n) {
        int t = ntype[i];
        int lane = threadIdx.x & 63;
        #pragma unroll
        for (int tt = 0; tt < NT; tt++) {
            bool me = (t == tt);
            unsigned long long m = __ballot(me);
            if (me) {
                int lower = __popcll(m & ((1ull << lane) - 1ull));
                if (lower == 0) atomicAdd(&tcnt[tt], __popcll(m));
            }
        }
    }
}

__global__ void k_scan(int n, int* offs, int* next, const int* tcnt, int* tnext, int* tstart) {
    __shared__ int part[1024];
    int tid = threadIdx.x;
    int chunk = (n + 1023) >> 10;
    int lo = tid * chunk, hi = min(lo + chunk, n);
    int s = 0;
    for (int i = lo; i < hi; i++) s += offs[i];
    part[tid] = s;
    __syncthreads();
    for (int d = 1; d < 1024; d <<= 1) {
        int v = (tid >= d) ? part[tid - d] : 0;
        __syncthreads();
        part[tid] += v;
        __syncthreads();
    }
    int run = (tid == 0) ? 0 : part[tid - 1];
    for (int i = lo; i < hi; i++) {
        int c = offs[i];
        offs[i] = run; next[i] = run;
        run += c;
    }
    if (tid == 0) {
        offs[n] = part[1023];
        int t0 = 0;
        for (int t = 0; t < NT; t++) { tnext[t] = t0; tstart[t] = t0; t0 += tcnt[t]; }
    }
}

__global__ void k_scatter(int n, int e, const int* src, const int* tgt, const int* etype,
                          const int* ntype, int* next, int* sorted, int* tnext, int* order) {
    int i = blockIdx.x * 256 + threadIdx.x;
    if (i < e) {
        int p = atomicAdd(&next[tgt[i]], 1);
        sorted[p] = i;
    }
    if (i < n) {
        int t = ntype[i];
        int lane = threadIdx.x & 63;
        #pragma unroll
        for (int tt = 0; tt < NT; tt++) {
            bool me = (t == tt);
            unsigned long long m = __ballot(me);
            if (me) {
                int lower = __popcll(m & ((1ull << lane) - 1ull));
                int leader = __ffsll((long long)m) - 1;
                int base = 0;
                if (lane == leader) base = atomicAdd(&tnext[tt], __popcll(m));
                base = __shfl(base, leader, 64);
                order[base + lower] = i;
            }
        }
    }
}

// ================= FAST PATH =================

// Combined weights: Kcomb[t,r][d][h*16+f] = sum_j Kw[t][d][16h+j] * Watt[r][h][j][f]
__global__ void k_comb(const float* Kw, const float* Kb, const float* r_att,
                       const float* Vw, const float* Vb, const float* r_msg,
                       ushort_t* Kcomb, float* kbc, ushort_t* Vcomb, float* vbc) {
    int kind = blockIdx.x / (NT * NR);
    int tr = blockIdx.x % (NT * NR);
    int t = tr / NR, r = tr % NR;
    const float* W0 = kind ? Vw : Kw;
    const float* B0 = kind ? Vb : Kb;
    const float* Wr = kind ? r_msg : r_att;
    ushort_t* outW = kind ? Vcomb : Kcomb;
    float* outB = kind ? vbc : kbc;
    int tid = threadIdx.x;           // 128 = (h,f)
    int h = tid >> 4, f = tid & 15;
    float wcol[16];
    #pragma unroll
    for (int j = 0; j < 16; j++) wcol[j] = Wr[(((size_t)r * NH + h) * DKK + j) * DKK + f];
    __shared__ float row[ND];
    for (int d = 0; d < ND; d++) {
        __syncthreads();
        row[tid] = W0[((size_t)t * ND + d) * ND + tid];
        __syncthreads();
        float s = 0.f;
        #pragma unroll
        for (int j = 0; j < 16; j++) s += row[h * DKK + j] * wcol[j];
        outW[((size_t)tr * ND + d) * ND + tid] = f2bf(s);
    }
    float sb = 0.f;
    #pragma unroll
    for (int j = 0; j < 16; j++) sb += B0[t * ND + h * DKK + j] * wcol[j];
    outB[tr * ND + tid] = sb;
}

// pack all 10 per-type weight matrices into MFMA B-fragment order + biases
__global__ void k_pack(const float* Qw, const float* Qb, const float* Vw, const float* Vb,
                       const ushort_t* Kcomb, const float* kbc,
                       const ushort_t* Vcomb, const float* vbc,
                       ushort_t* Wall, float* bcat) {
    int blk = blockIdx.x;
    int kb = blk & 3;
    int c = (blk >> 2) & 7;
    int tm = blk >> 5;
    int m = tm % NMAT, t = tm / NMAT;
    int lane = threadIdx.x;
    int nn = c * 16 + (lane & 15);
    int quad = lane >> 4;
    ushort_t* dst = Wall + (size_t)blk * 512 + lane * 8;
    #pragma unroll
    for (int j = 0; j < 8; j++) {
        int k = kb * 32 + quad * 8 + j;
        float w;
        if (m == 0)      w = Qw[((size_t)t * ND + k) * ND + nn];
        else if (m <= 4) w = bf2f(Kcomb[((size_t)(t * NR + m - 1) * ND + k) * ND + nn]);
        else if (m == 5) w = Vw[((size_t)(ND + k)) * ND + nn];   // type-1 V
        else             w = bf2f(Vcomb[((size_t)(t * NR + m - 6) * ND + k) * ND + nn]);
        dst[j] = f2bf(w);
    }
    if (kb == 0 && quad == 0) {
        float b;
        if (m == 0)      b = Qb[t * ND + nn];
        else if (m <= 4) b = kbc[(t * NR + m - 1) * ND + nn];
        else if (m == 5) b = Vb[ND + nn];
        else             b = vbc[(t * NR + m - 6) * ND + nn];
        bcat[(t * NMAT + m) * ND + nn] = b;
    }
}

// MFMA projection: every block is type-uniform by construction (padded type segments)
__global__ void __launch_bounds__(256) k_projm(
    int n, const float* x_in, const int* order,
    const int* tcnt, const int* tstart,
    const ushort_t* Wall, const float* bcat,
    int m0, int nm,
    ushort_t* out_qn, ushort_t* out_kt, ushort_t* out_v1, ushort_t* out_vt)
{
    __shared__ __align__(16) ushort_t xs[4096];  // A-fragment-permuted bf16: [rt][kb][lane][8]
    __shared__ int nodes[32];
    // block -> (type, local tile)
    int b = blockIdx.x;
    int nb0 = (tcnt[0] + 31) >> 5, nb1 = (tcnt[1] + 31) >> 5, nb2 = (tcnt[2] + 31) >> 5;
    int t, lb;
    if (b < nb0)                  { t = 0; lb = b; }
    else if (b < nb0 + nb1)       { t = 1; lb = b - nb0; }
    else if (b < nb0 + nb1 + nb2) { t = 2; lb = b - nb0 - nb1; }
    else return;
    int segoff = lb * 32;
    int cnt = min(32, tcnt[t] - segoff);
    int segbase = tstart[t] + segoff;
    int tid = threadIdx.x;
    if (tid < 32) nodes[tid] = (tid < cnt) ? order[segbase + tid] : -1;
    __syncthreads();
    // stage x -> permuted bf16, two contiguous 16B writes per thread (conflict-free)
    {
        int row = tid >> 3;
        int d0 = (tid & 7) * 16;
        int rt = row >> 4, rl = row & 15;
        int kb = d0 >> 5, q0 = (d0 >> 3) & 3;
        uint4 c0, c1;
        if (row < cnt) {
            const float4* xp4 = (const float4*)(x_in + (size_t)nodes[row] * ND + d0);
            float4 a = xp4[0], b2 = xp4[1], c2 = xp4[2], d4 = xp4[3];
            c0.x = pk2(a.x, a.y);   c0.y = pk2(a.z, a.w);
            c0.z = pk2(b2.x, b2.y); c0.w = pk2(b2.z, b2.w);
            c1.x = pk2(c2.x, c2.y); c1.y = pk2(c2.z, c2.w);
            c1.z = pk2(d4.x, d4.y); c1.w = pk2(d4.z, d4.w);
        } else {
            c0.x = c0.y = c0.z = c0.w = 0u;
            c1 = c0;
        }
        *(uint4*)&xs[((rt * 4 + kb) * 64 + q0 * 16 + rl) * 8]       = c0;
        *(uint4*)&xs[((rt * 4 + kb) * 64 + (q0 + 1) * 16 + rl) * 8] = c1;
    }
    __syncthreads();

    int w = tid >> 6, lane = tid & 63;
    int rt = w & 1;                      // wave's row-tile (16 nodes)
    bf16x8 afr[4];
    #pragma unroll
    for (int kb = 0; kb < 4; kb++)
        afr[kb] = as_bf16x8(*(const uint4*)&xs[((rt * 4 + kb) * 64 + lane) * 8]);
    int nct = nm * 8;
    for (int ct = (w >> 1); ct < nct; ct += 2) {
        int m = m0 + (ct >> 3), c = ct & 7;
        const uint4* bp = (const uint4*)(Wall + ((((size_t)t * NMAT + m) * 8 + c) * 4) * 512);
        f32x4 acc = {0.f, 0.f, 0.f, 0.f};
        #pragma unroll
        for (int kb = 0; kb < 4; kb++) {
            bf16x8 bfr = as_bf16x8(bp[kb * 64 + lane]);
            acc = __builtin_amdgcn_mfma_f32_16x16x32_bf16(afr[kb], bfr, acc, 0, 0, 0);
        }
        int col = c * 16 + (lane & 15);
        float bias = bcat[(t * NMAT + m) * ND + col];
        int rbase = rt * 16 + (lane >> 4) * 4;
        #pragma unroll
        for (int r = 0; r < 4; r++) {
            int grow = rbase + r;
            if (grow >= cnt) continue;
            int node = nodes[grow];
            ushort_t val = f2bf(acc[r] + bias);
            if (m == 0)       out_qn[(size_t)node * ND + col] = val;
            else if (m <= 4)  out_kt[((size_t)node * NR + (m - 1)) * ND + col] = val;
            else if (m == 5)  out_v1[(size_t)node * ND + col] = val;
            else              out_vt[((size_t)node * NR + (m - 6)) * ND + col] = val;
        }
    }
}

// Fused logits + online segment softmax, wave per target node.
// Writes raw logits in SORTED order (atts[p]) + bf16 row max + denom.
__global__ void k_attmd(int n, const int* off, const int* sorted, const int* src,
                        const int* etype, const int* ntype,
                        const ushort_t* qn, const ushort_t* kt, const float* r_pri,
                        float* atts, ushort_t* mb, float* db) {
    int wv = threadIdx.x >> 6, lane = threadIdx.x & 63;
    int i = blockIdx.x * 4 + wv;
    if (i >= n) return;
    int h = lane >> 3;
    int tt = ntype[i];
    unsigned int qu = *(const unsigned int*)(qn + (size_t)i * ND + lane * 2);
    float q0 = bf2f(qu & 0xffff), q1 = bf2f(qu >> 16);
    int d0 = off[i], d1 = off[i + 1];
    float m = -3.0e38f, den = 0.f;
    #pragma unroll 2
    for (int p = d0; p < d1; p++) {
        int ee = sorted[p];
        int s = src[ee], r = etype[ee];
        unsigned int ku = *(const unsigned int*)(kt + ((size_t)s * NR + r) * ND + lane * 2);
        float partial = q0 * bf2f(ku & 0xffff) + q1 * bf2f(ku >> 16);
        partial += __shfl_xor(partial, 1, 64);
        partial += __shfl_xor(partial, 2, 64);
        partial += __shfl_xor(partial, 4, 64);
        float pri = r_pri[((tt * NR + r) * NT + ntype[s]) * NH + h];
        float logit = fminf(fmaxf(partial * pri * 0.25f, -1.0e4f), 1.0e4f);
        if ((lane & 7) == 0) atts[(size_t)p * NH + h] = logit;
        float mnew = fmaxf(m, logit);
        den = den * expf(m - mnew) + expf(logit - mnew);
        m = mnew;
    }
    ushort_t mh = (d1 > d0) ? f2bf(m) : (ushort_t)0;
    den = (d1 > d0) ? den * expf(m - bf2f(mh)) : 0.f;
    if ((lane & 7) == 0) { mb[i * NH + h] = mh; db[i * NH + h] = den; }
}

// wave-per-node aggregation; softmax normalize folded in; atts read sequentially
__global__ void k_aggr_fast(int n, const int* off, const int* sorted, const int* src,
                            const int* etype, const ushort_t* vt, const float* atts,
                            const ushort_t* mb, const float* db, float* aggr) {
    int wv = threadIdx.x >> 6, lane = threadIdx.x & 63;
    int i = blockIdx.x * 4 + wv;
    if (i >= n) return;
    int h = lane >> 3;
    float mref = bf2f(mb[i * NH + h]);
    float inv = 1.f / (db[i * NH + h] + 1e-16f);
    int d0 = off[i], d1 = off[i + 1];
    float acc0 = 0.f, acc1 = 0.f;
    #pragma unroll 2
    for (int p = d0; p < d1; p++) {
        int ee = sorted[p];
        int s = src[ee], r = etype[ee];
        float w = expf(atts[(size_t)p * NH + h] - mref) * inv;
        unsigned int u = *reinterpret_cast<const unsigned int*>(
            vt + ((size_t)s * NR + r) * ND + lane * 2);
        acc0 += w * bf2f(u & 0xffff);
        acc1 += w * bf2f(u >> 16);
    }
    float2 o; o.x = acc0; o.y = acc1;
    *reinterpret_cast<float2*>(aggr + (size_t)i * ND + lane * 2) = o;
}

// ================= FALLBACK PATH (round-3 proven kernels) =================

__global__ void k_proj(int n, const float* x_in, const int* ntype, const int* order,
                       const float* Kw, const float* Kb,
                       const float* Qw, const float* Qb,
                       const float* Vw, const float* Vb,
                       ushort_t* kn, ushort_t* qn, ushort_t* vn, ushort_t* v1) {
    __shared__ float xs[NB][ND];
    __shared__ int nodes[NB];
    __shared__ int types[NB];
    int tid = threadIdx.x;
    int base = blockIdx.x * NB;
    int cnt = min(NB, n - base);
    if (tid < cnt) { int nd = order[base + tid]; nodes[tid] = nd; types[tid] = ntype[nd]; }
    __syncthreads();
    for (int j = 0; j < cnt; j++) xs[j][tid] = x_in[(size_t)nodes[j] * ND + tid];
    __syncthreads();
    bool uni = (types[0] == types[cnt - 1]);
    for (int m = 0; m < 4; m++) {
        const float *W, *B; ushort_t* out; int forced_t = -1;
        if (m == 0)      { W = Kw; B = Kb; out = kn; }
        else if (m == 1) { W = Qw; B = Qb; out = qn; }
        else if (m == 2) { W = Vw; B = Vb; out = vn; }
        else             { W = Vw; B = Vb; out = v1; forced_t = 1; }
        if (uni || forced_t >= 0) {
            int t = (forced_t >= 0) ? forced_t : types[0];
            float bias = B[t * ND + tid];
            float acc[NB];
            #pragma unroll
            for (int j = 0; j < NB; j++) acc[j] = bias;
            const float* Wp = W + (size_t)t * ND * ND + tid;
            for (int d = 0; d < ND; d++) {
                float w = Wp[(size_t)d * ND];
                #pragma unroll
                for (int j = 0; j < NB; j++) acc[j] += xs[j][d] * w;
            }
            for (int j = 0; j < cnt; j++) out[(size_t)nodes[j] * ND + tid] = f2bf(acc[j]);
        } else {
            for (int j = 0; j < cnt; j++) {
                int t = types[j];
                float acc = B[t * ND + tid];
                const float* Wp = W + (size_t)t * ND * ND + tid;
                for (int d = 0; d < ND; d++) acc += xs[j][d] * Wp[(size_t)d * ND];
                out[(size_t)nodes[j] * ND + tid] = f2bf(acc);
            }
        }
    }
}

__global__ void k_att(int e, const int* src, const int* tgt, const int* etype, const int* ntype,
                      const ushort_t* kn, const ushort_t* qn,
                      const float* r_att, const float* r_pri, float* att) {
    int id = blockIdx.x * 256 + threadIdx.x;
    if (id >= e * NH) return;
    int ee = id >> 3, h = id & 7;
    int s = src[ee], t = tgt[ee], r = etype[ee];
    float kf[16], qf[16];
    load_bf8(kn + (size_t)s * ND + h * DKK, kf);
    load_bf8(kn + (size_t)s * ND + h * DKK + 8, kf + 8);
    load_bf8(qn + (size_t)t * ND + h * DKK, qf);
    load_bf8(qn + (size_t)t * ND + h * DKK + 8, qf + 8);
    const float* W = r_att + (size_t)(r * NH + h) * DKK * DKK;
    float kt[16];
    #pragma unroll
    for (int f = 0; f < 16; f++) kt[f] = 0.f;
    #pragma unroll 4
    for (int d = 0; d < 16; d++) {
        float kd = kf[d];
        #pragma unroll
        for (int f = 0; f < 16; f++) kt[f] += kd * W[d * 16 + f];
    }
    float a = 0.f;
    #pragma unroll
    for (int f = 0; f < 16; f++) a += qf[f] * kt[f];
    int tt = ntype[t], st = ntype[s];
    float pri = r_pri[((tt * NR + r) * NT + st) * NH + h];
    float logit = a * pri * 0.25f;
    logit = fminf(fmaxf(logit, -1.0e4f), 1.0e4f);
    att[(size_t)ee * NH + h] = logit;
}

__global__ void k_mden(int n, const int* off, const int* sorted,
                       const float* att, ushort_t* mb, float* db) {
    int id = blockIdx.x * 256 + threadIdx.x;
    if (id >= n * NH) return;
    int i = id >> 3, h = id & 7;
    int d0 = off[i], d1 = off[i + 1];
    float m = -3.0e38f;
    for (int p = d0; p < d1; p++) m = fmaxf(m, att[(size_t)sorted[p] * NH + h]);
    ushort_t mh = (d1 > d0) ? f2bf(m) : (ushort_t)0;
    float mref = bf2f(mh);
    float den = 0.f;
    for (int p = d0; p < d1; p++) den += expf(att[(size_t)sorted[p] * NH + h] - mref);
    mb[id] = mh;
    db[id] = den;
}

__global__ void k_norm(int e, const int* tgt, const ushort_t* mb, const float* db, float* att) {
    int id = blockIdx.x * 256 + threadIdx.x;
    if (id >= e * NH) return;
    int ee = id >> 3, h = id & 7;
    int t = tgt[ee];
    float w = expf(att[id] - bf2f(mb[t * NH + h])) / (db[t * NH + h] + 1e-16f);
    att[id] = w;
}

__global__ void k_aggr(int n, const int* off, const int* sorted, const int* src, const int* etype,
                       const ushort_t* vn, const float* r_msg, const float* att, float* aggr) {
    int wv = threadIdx.x >> 6, lane = threadIdx.x & 63;
    int i = blockIdx.x * 4 + wv;
    if (i >= n) return;
    int h = lane >> 3, f0 = (lane & 7) * 2;
    int d0 = off[i], d1 = off[i + 1];
    float acc0 = 0.f, acc1 = 0.f;
    for (int p = d0; p < d1; p++) {
        int ee = sorted[p];
        int s = src[ee], r = etype[ee];
        float w = att[(size_t)ee * NH + h];
        float vj[16];
        load_bf8(vn + (size_t)s * ND + h * DKK, vj);
        load_bf8(vn + (size_t)s * ND + h * DKK + 8, vj + 8);
        const float* Wm = r_msg + (size_t)(r * NH + h) * DKK * DKK + f0;
        float a0 = 0.f, a1 = 0.f;
        #pragma unroll
        for (int d = 0; d < 16; d++) {
            a0 += vj[d] * Wm[d * 16];
            a1 += vj[d] * Wm[d * 16 + 1];
        }
        acc0 += w * a0; acc1 += w * a1;
    }
    aggr[(size_t)i * ND + h * DKK + f0]     = acc0;
    aggr[(size_t)i * ND + h * DKK + f0 + 1] = acc1;
}

// ---------------- shared epilogue ----------------

__global__ void k_spk(int n, const int* winner, const int* tgt, const ushort_t* v1,
                      const float* s2u, float* aggr) {
    __shared__ float xs[NB][ND];
    __shared__ int wn[NB];
    int tid = threadIdx.x;
    int base = blockIdx.x * NB;
    int cnt = min(NB, n - base);
    if (tid < cnt) wn[tid] = winner[base + tid];
    __syncthreads();
    for (int j = 0; j < cnt; j++) {
        int w = wn[j];
        xs[j][tid] = (w >= 0) ? bf2f(v1[(size_t)tgt[w] * ND + tid]) : 0.f;
    }
    __syncthreads();
    float acc[NB];
    #pragma unroll
    for (int j = 0; j < NB; j++) acc[j] = 0.f;
    const float* Wp = s2u + tid;
    for (int d = 0; d < ND; d++) {
        float w = Wp[(size_t)d * ND];
        #pragma unroll
        for (int j = 0; j < NB; j++) acc[j] += xs[j][d] * w;
    }
    for (int j = 0; j < cnt; j++) {
        size_t idx = (size_t)(base + j) * ND + tid;
        float g = aggr[idx] + acc[j];
        g = 0.5f * g * (1.f + erff(g * 0.70710678118f));
        aggr[idx] = g;
    }
}

__global__ void k_final(int n, const float* x_in, const int* ntype, const int* order,
                        const float* Aw, const float* Ab, const float* skip,
                        const float* aggr, float* out) {
    __shared__ float xs[NB][ND];
    __shared__ int nodes[NB];
    __shared__ int types[NB];
    int tid = threadIdx.x;
    int base = blockIdx.x * NB;
    int cnt = min(NB, n - base);
    if (tid < cnt) { int nd = order[base + tid]; nodes[tid] = nd; types[tid] = ntype[nd]; }
    __syncthreads();
    for (int j = 0; j < cnt; j++) xs[j][tid] = aggr[(size_t)nodes[j] * ND + tid];
    __syncthreads();
    bool uni = (types[0] == types[cnt - 1]);
    if (uni) {
        int t = types[0];
        float bias = Ab[t * ND + tid];
        float acc[NB];
        #pragma unroll
        for (int j = 0; j < NB; j++) acc[j] = bias;
        const float* Wp = Aw + (size_t)t * ND * ND + tid;
        for (int d = 0; d < ND; d++) {
            float w = Wp[(size_t)d * ND];
            #pragma unroll
            for (int j = 0; j < NB; j++) acc[j] += xs[j][d] * w;
        }
        float alpha = 1.f / (1.f + expf(-skip[t]));
        for (int j = 0; j < cnt; j++) {
            float xin = x_in[(size_t)nodes[j] * ND + tid];
            out[(size_t)nodes[j] * ND + tid] = acc[j] * alpha + xin * (1.f - alpha);
        }
    } else {
        for (int j = 0; j < cnt; j++) {
            int t = types[j];
            float acc = Ab[t * ND + tid];
            const float* Wp = Aw + (size_t)t * ND * ND + tid;
            for (int d = 0; d < ND; d++) acc += xs[j][d] * Wp[(size_t)d * ND];
            float alpha = 1.f / (1.f + expf(-skip[t]));
            float xin = x_in[(size_t)nodes[j] * ND + tid];
            out[(size_t)nodes[j] * ND + tid] = acc * alpha + xin * (1.f - alpha);
        }
    }
}

extern "C" void kernel_launch(void* const* d_in, const int* in_sizes, int n_in,
                              void* d_out, int out_size, void* d_ws, size_t ws_size,
                              hipStream_t stream) {
    const float* node_inp = (const float*)d_in[0];
    const int* node_type  = (const int*)d_in[1];
    const int* edge_index = (const int*)d_in[2];
    const int* edge_type  = (const int*)d_in[3];
    const float* Kw = (const float*)d_in[5];
    const float* Kb = (const float*)d_in[6];
    const float* Qw = (const float*)d_in[7];
    const float* Qb = (const float*)d_in[8];
    const float* Vw = (const float*)d_in[9];
    const float* Vb = (const float*)d_in[10];
    const float* Aw = (const float*)d_in[11];
    const float* Ab = (const float*)d_in[12];
    const float* r_pri = (const float*)d_in[13];
    const float* r_att = (const float*)d_in[14];
    const float* r_msg = (const float*)d_in[15];
    const float* s2u   = (const float*)d_in[16];
    const float* skip  = (const float*)d_in[17];

    int n = in_sizes[1];
    int e = in_sizes[3];
    const int* srcp = edge_index;
    const int* tgtp = edge_index + e;

    char* wsp = (char*)d_ws;
    size_t woff = 0;
    auto alloc = [&](size_t b) { void* p = wsp + woff; woff += (b + 255) & ~(size_t)255; return p; };

    // ---- common infra ----
    int* offs     = (int*)alloc((size_t)(n + 1) * 4);
    int* nxt      = (int*)alloc((size_t)n * 4);
    int* winner   = (int*)alloc((size_t)n * 4);
    int* order    = (int*)alloc((size_t)n * 4);
    int* tcnt     = (int*)alloc(16);
    int* tnext    = (int*)alloc(16);
    int* tstart   = (int*)alloc(16);
    int* sorted   = (int*)alloc((size_t)e * 4);
    ushort_t* mb  = (ushort_t*)alloc((size_t)n * NH * 2);
    float* db     = (float*)alloc((size_t)n * NH * 4);
    ushort_t* v1b = (ushort_t*)alloc((size_t)n * ND * 2);
    float* att    = (float*)alloc((size_t)e * NH * 4);
    size_t commonEnd = woff;

    // ---- fast-path extra layout ----
    ushort_t* Kcomb = (ushort_t*)alloc((size_t)NT * NR * ND * ND * 2);
    ushort_t* Vcomb = (ushort_t*)alloc((size_t)NT * NR * ND * ND * 2);
    float* kbc      = (float*)alloc((size_t)NT * NR * ND * 4);
    float* vbc      = (float*)alloc((size_t)NT * NR * ND * 4);
    ushort_t* Wall  = (ushort_t*)alloc((size_t)NT * NMAT * 8 * 4 * 512 * 2);
    float* bcat     = (float*)alloc((size_t)NT * NMAT * ND * 4);
    char* F         = (char*)alloc((size_t)n * 1536);   // phase1: qn+kt; phase2: vt+aggr
    size_t fastEnd = woff;

    int gn = (n + 255) / 256;
    int ge = (e + 255) / 256;

    k_zero<<<gn, 256, 0, stream>>>(n, offs, winner, tcnt);
    k_count<<<ge, 256, 0, stream>>>(n, e, srcp, tgtp, edge_type, node_type, offs, winner, tcnt);
    k_scan<<<1, 1024, 0, stream>>>(n, offs, nxt, tcnt, tnext, tstart);
    k_scatter<<<ge, 256, 0, stream>>>(n, e, srcp, tgtp, edge_type, node_type, nxt, sorted, tnext, order);

    if (ws_size >= fastEnd) {
        // ======== FAST PATH ========
        ushort_t* qn  = (ushort_t*)F;
        ushort_t* kt  = (ushort_t*)(F + (size_t)n * 256);
        ushort_t* vt  = (ushort_t*)F;                         // overlays qn+kt (dead after k_attmd)
        float* aggr   = (float*)(F + (size_t)n * 1024);       // overlays kt tail (dead)
        int gproj = (n + 31) / 32 + NT;                       // upper bound on padded tiles

        k_comb<<<2 * NT * NR, 128, 0, stream>>>(Kw, Kb, r_att, Vw, Vb, r_msg,
                                                Kcomb, kbc, Vcomb, vbc);
        k_pack<<<NT * NMAT * 8 * 4, 64, 0, stream>>>(Qw, Qb, Vw, Vb, Kcomb, kbc,
                                                     Vcomb, vbc, Wall, bcat);
        // phase1: mats 0..5 -> qn, kt, v1b
        k_projm<<<gproj, 256, 0, stream>>>(n, node_inp, order, tcnt, tstart, Wall, bcat,
                                           0, 6, qn, kt, v1b, (ushort_t*)nullptr);
        // fused logits + online softmax (sorted-order logits)
        k_attmd<<<(n + 3) / 4, 256, 0, stream>>>(n, offs, sorted, srcp, edge_type, node_type,
                                                 qn, kt, r_pri, att, mb, db);
        // phase2: mats 6..9 -> vt (overlays qn/kt)
        k_projm<<<gproj, 256, 0, stream>>>(n, node_inp, order, tcnt, tstart, Wall, bcat,
                                           6, 4, (ushort_t*)nullptr, (ushort_t*)nullptr,
                                           (ushort_t*)nullptr, vt);
        k_aggr_fast<<<(n + 3) / 4, 256, 0, stream>>>(n, offs, sorted, srcp, edge_type,
                                                     vt, att, mb, db, aggr);
        k_spk<<<(n + NB - 1) / NB, 128, 0, stream>>>(n, winner, tgtp, v1b, s2u, aggr);
        k_final<<<(n + NB - 1) / NB, 128, 0, stream>>>(n, node_inp, node_type, order,
                                                       Aw, Ab, skip, aggr, (float*)d_out);
    } else {
        // ======== FALLBACK (round-3 layout, proven) ========
        woff = commonEnd;
        ushort_t* vn  = (ushort_t*)alloc((size_t)n * ND * 2);
        char* regA    = (char*)alloc((size_t)n * ND * 2 * 2);
        ushort_t* kn  = (ushort_t*)regA;
        ushort_t* qn  = (ushort_t*)(regA + (size_t)n * ND * 2);
        float* aggr   = (float*)regA;

        k_proj<<<(n + NB - 1) / NB, 128, 0, stream>>>(n, node_inp, node_type, order,
                                                      Kw, Kb, Qw, Qb, Vw, Vb, kn, qn, vn, v1b);
        k_att<<<(e * NH + 255) / 256, 256, 0, stream>>>(e, srcp, tgtp, edge_type, node_type,
                                                        kn, qn, r_att, r_pri, att);
        k_mden<<<(n * NH + 255) / 256, 256, 0, stream>>>(n, offs, sorted, att, mb, db);
        k_norm<<<(e * NH + 255) / 256, 256, 0, stream>>>(e, tgtp, mb, db, att);
        k_aggr<<<(n + 3) / 4, 256, 0, stream>>>(n, offs, sorted, srcp, edge_type, vn, r_msg, att, aggr);
        k_spk<<<(n + NB - 1) / NB, 128, 0, stream>>>(n, winner, tgtp, v1b, s2u, aggr);
        k_final<<<(n + NB - 1) / NB, 128, 0, stream>>>(n, node_inp, node_type, order,
                                                       Aw, Ab, skip, aggr, (float*)d_out);
    }
}

// Round 9
// 552.059 us; speedup vs baseline: 1.2169x; 1.2169x over previous
//
#include <hip/hip_runtime.h>
#include <hip/hip_bf16.h>
#include <math.h>

#define ND 128
#define NH 8
#define DKK 16
#define NT 3
#define NR 4
#define NB 8
#define NMAT 10   // packed mats: 0=Q, 1..4=Kcomb[r], 5=V(type1), 6..9=Vcomb[r]

typedef unsigned short ushort_t;
typedef __bf16 bf16_t;
typedef bf16_t bf16x8 __attribute__((ext_vector_type(8)));
typedef float f32x4 __attribute__((ext_vector_type(4)));

__device__ __forceinline__ float bf2f(unsigned short u) {
    union { unsigned int i; float f; } v; v.i = ((unsigned int)u) << 16; return v.f;
}
__device__ __forceinline__ unsigned short f2bf(float f) {
    union { float f; unsigned int i; } v; v.f = f;
    unsigned int x = v.i;
    unsigned int lsb = (x >> 16) & 1u;
    x += 0x7fffu + lsb;
    return (unsigned short)(x >> 16);
}
__device__ __forceinline__ unsigned int pk2(float a, float b) {
    return (unsigned int)f2bf(a) | ((unsigned int)f2bf(b) << 16);
}
__device__ __forceinline__ void load_bf8(const ushort_t* p, float* o) {
    uint4 u = *reinterpret_cast<const uint4*>(p);
    o[0]=bf2f(u.x & 0xffff); o[1]=bf2f(u.x >> 16);
    o[2]=bf2f(u.y & 0xffff); o[3]=bf2f(u.y >> 16);
    o[4]=bf2f(u.z & 0xffff); o[5]=bf2f(u.z >> 16);
    o[6]=bf2f(u.w & 0xffff); o[7]=bf2f(u.w >> 16);
}
__device__ __forceinline__ bf16x8 as_bf16x8(uint4 u) {
    union { uint4 u; bf16x8 v; } c; c.u = u; return c.v;
}

// ---------------- sort / bucket infrastructure ----------------

__global__ void k_zero(int n, int* offs, int* winner, int* tcnt) {
    int i = blockIdx.x * 256 + threadIdx.x;
    if (i < n) { offs[i] = 0; winner[i] = -1; }
    if (i < NT) tcnt[i] = 0;
}

// wave-aggregated 3-bin atomics
__global__ void k_count(int n, int e, const int* src, const int* tgt, const int* etype,
                        const int* ntype, int* offs, int* winner, int* tcnt) {
    int i = blockIdx.x * 256 + threadIdx.x;
    if (i < e) {
        atomicAdd(&offs[tgt[i]], 1);
        if (etype[i] == 0) atomicMax(&winner[src[i]], i);  // numpy last-write-wins == max edge id
    }
    if (i < n) {
        int t = ntype[i];
        int lane = threadIdx.x & 63;
        #pragma unroll
        for (int tt = 0; tt < NT; tt++) {
            bool me = (t == tt);
            unsigned long long m = __ballot(me);
            if (me) {
                int lower = __popcll(m & ((1ull << lane) - 1ull));
                if (lower == 0) atomicAdd(&tcnt[tt], __popcll(m));
            }
        }
    }
}

__global__ void k_scan(int n, int* offs, int* next, const int* tcnt, int* tnext, int* tstart) {
    __shared__ int part[1024];
    int tid = threadIdx.x;
    int chunk = (n + 1023) >> 10;
    int lo = tid * chunk, hi = min(lo + chunk, n);
    int s = 0;
    for (int i = lo; i < hi; i++) s += offs[i];
    part[tid] = s;
    __syncthreads();
    for (int d = 1; d < 1024; d <<= 1) {
        int v = (tid >= d) ? part[tid - d] : 0;
        __syncthreads();
        part[tid] += v;
        __syncthreads();
    }
    int run = (tid == 0) ? 0 : part[tid - 1];
    for (int i = lo; i < hi; i++) {
        int c = offs[i];
        offs[i] = run; next[i] = run;
        run += c;
    }
    if (tid == 0) {
        offs[n] = part[1023];
        int t0 = 0;
        for (int t = 0; t < NT; t++) { tnext[t] = t0; tstart[t] = t0; t0 += tcnt[t]; }
    }
}

// mode=1 (fast): eord[p] = (src*NR+etype) | ntype[src]<<28 ; mode=0: eord[p] = edge id
__global__ void k_scatter(int n, int e, const int* src, const int* tgt, const int* etype,
                          const int* ntype, int* next, int* eord, int mode,
                          int* tnext, int* order) {
    int i = blockIdx.x * 256 + threadIdx.x;
    if (i < e) {
        int p = atomicAdd(&next[tgt[i]], 1);
        if (mode) {
            int s = src[i];
            eord[p] = (s * NR + etype[i]) | (ntype[s] << 28);
        } else {
            eord[p] = i;
        }
    }
    if (i < n) {
        int t = ntype[i];
        int lane = threadIdx.x & 63;
        #pragma unroll
        for (int tt = 0; tt < NT; tt++) {
            bool me = (t == tt);
            unsigned long long m = __ballot(me);
            if (me) {
                int lower = __popcll(m & ((1ull << lane) - 1ull));
                int leader = __ffsll((long long)m) - 1;
                int base = 0;
                if (lane == leader) base = atomicAdd(&tnext[tt], __popcll(m));
                base = __shfl(base, leader, 64);
                order[base + lower] = i;
            }
        }
    }
}

// ================= FAST PATH =================

// Combined weights: Kcomb[t,r][d][h*16+f] = sum_j Kw[t][d][16h+j] * Watt[r][h][j][f]
__global__ void k_comb(const float* Kw, const float* Kb, const float* r_att,
                       const float* Vw, const float* Vb, const float* r_msg,
                       ushort_t* Kcomb, float* kbc, ushort_t* Vcomb, float* vbc) {
    int kind = blockIdx.x / (NT * NR);
    int tr = blockIdx.x % (NT * NR);
    int t = tr / NR, r = tr % NR;
    const float* W0 = kind ? Vw : Kw;
    const float* B0 = kind ? Vb : Kb;
    const float* Wr = kind ? r_msg : r_att;
    ushort_t* outW = kind ? Vcomb : Kcomb;
    float* outB = kind ? vbc : kbc;
    int tid = threadIdx.x;           // 128 = (h,f)
    int h = tid >> 4, f = tid & 15;
    float wcol[16];
    #pragma unroll
    for (int j = 0; j < 16; j++) wcol[j] = Wr[(((size_t)r * NH + h) * DKK + j) * DKK + f];
    __shared__ float row[ND];
    for (int d = 0; d < ND; d++) {
        __syncthreads();
        row[tid] = W0[((size_t)t * ND + d) * ND + tid];
        __syncthreads();
        float s = 0.f;
        #pragma unroll
        for (int j = 0; j < 16; j++) s += row[h * DKK + j] * wcol[j];
        outW[((size_t)tr * ND + d) * ND + tid] = f2bf(s);
    }
    float sb = 0.f;
    #pragma unroll
    for (int j = 0; j < 16; j++) sb += B0[t * ND + h * DKK + j] * wcol[j];
    outB[tr * ND + tid] = sb;
}

// pack all 10 per-type weight matrices into MFMA B-fragment order + biases
__global__ void k_pack(const float* Qw, const float* Qb, const float* Vw, const float* Vb,
                       const ushort_t* Kcomb, const float* kbc,
                       const ushort_t* Vcomb, const float* vbc,
                       ushort_t* Wall, float* bcat) {
    int blk = blockIdx.x;
    int kb = blk & 3;
    int c = (blk >> 2) & 7;
    int tm = blk >> 5;
    int m = tm % NMAT, t = tm / NMAT;
    int lane = threadIdx.x;
    int nn = c * 16 + (lane & 15);
    int quad = lane >> 4;
    ushort_t* dst = Wall + (size_t)blk * 512 + lane * 8;
    #pragma unroll
    for (int j = 0; j < 8; j++) {
        int k = kb * 32 + quad * 8 + j;
        float w;
        if (m == 0)      w = Qw[((size_t)t * ND + k) * ND + nn];
        else if (m <= 4) w = bf2f(Kcomb[((size_t)(t * NR + m - 1) * ND + k) * ND + nn]);
        else if (m == 5) w = Vw[((size_t)(ND + k)) * ND + nn];   // type-1 V
        else             w = bf2f(Vcomb[((size_t)(t * NR + m - 6) * ND + k) * ND + nn]);
        dst[j] = f2bf(w);
    }
    if (kb == 0 && quad == 0) {
        float b;
        if (m == 0)      b = Qb[t * ND + nn];
        else if (m <= 4) b = kbc[(t * NR + m - 1) * ND + nn];
        else if (m == 5) b = Vb[ND + nn];
        else             b = vbc[(t * NR + m - 6) * ND + nn];
        bcat[(t * NMAT + m) * ND + nn] = b;
    }
}

// MFMA projection: every block is type-uniform by construction (padded type segments)
__global__ void __launch_bounds__(256) k_projm(
    int n, const float* x_in, const int* order,
    const int* tcnt, const int* tstart,
    const ushort_t* Wall, const float* bcat,
    int m0, int nm,
    ushort_t* out_qn, ushort_t* out_kt, ushort_t* out_v1, ushort_t* out_vt)
{
    __shared__ __align__(16) ushort_t xs[4096];  // A-fragment-permuted bf16: [rt][kb][lane][8]
    __shared__ int nodes[32];
    // block -> (type, local tile)
    int b = blockIdx.x;
    int nb0 = (tcnt[0] + 31) >> 5, nb1 = (tcnt[1] + 31) >> 5, nb2 = (tcnt[2] + 31) >> 5;
    int t, lb;
    if (b < nb0)                  { t = 0; lb = b; }
    else if (b < nb0 + nb1)       { t = 1; lb = b - nb0; }
    else if (b < nb0 + nb1 + nb2) { t = 2; lb = b - nb0 - nb1; }
    else return;
    int segoff = lb * 32;
    int cnt = min(32, tcnt[t] - segoff);
    int segbase = tstart[t] + segoff;
    int tid = threadIdx.x;
    if (tid < 32) nodes[tid] = (tid < cnt) ? order[segbase + tid] : -1;
    __syncthreads();
    // stage x -> permuted bf16, two contiguous 16B writes per thread (conflict-free)
    {
        int row = tid >> 3;
        int d0 = (tid & 7) * 16;
        int rt = row >> 4, rl = row & 15;
        int kb = d0 >> 5, q0 = (d0 >> 3) & 3;
        uint4 c0, c1;
        if (row < cnt) {
            const float4* xp4 = (const float4*)(x_in + (size_t)nodes[row] * ND + d0);
            float4 a = xp4[0], b2 = xp4[1], c2 = xp4[2], d4 = xp4[3];
            c0.x = pk2(a.x, a.y);   c0.y = pk2(a.z, a.w);
            c0.z = pk2(b2.x, b2.y); c0.w = pk2(b2.z, b2.w);
            c1.x = pk2(c2.x, c2.y); c1.y = pk2(c2.z, c2.w);
            c1.z = pk2(d4.x, d4.y); c1.w = pk2(d4.z, d4.w);
        } else {
            c0.x = c0.y = c0.z = c0.w = 0u;
            c1 = c0;
        }
        *(uint4*)&xs[((rt * 4 + kb) * 64 + q0 * 16 + rl) * 8]       = c0;
        *(uint4*)&xs[((rt * 4 + kb) * 64 + (q0 + 1) * 16 + rl) * 8] = c1;
    }
    __syncthreads();

    int w = tid >> 6, lane = tid & 63;
    int rt = w & 1;                      // wave's row-tile (16 nodes)
    bf16x8 afr[4];
    #pragma unroll
    for (int kb = 0; kb < 4; kb++)
        afr[kb] = as_bf16x8(*(const uint4*)&xs[((rt * 4 + kb) * 64 + lane) * 8]);
    int nct = nm * 8;
    for (int ct = (w >> 1); ct < nct; ct += 2) {
        int m = m0 + (ct >> 3), c = ct & 7;
        const uint4* bp = (const uint4*)(Wall + ((((size_t)t * NMAT + m) * 8 + c) * 4) * 512);
        f32x4 acc = {0.f, 0.f, 0.f, 0.f};
        #pragma unroll
        for (int kb = 0; kb < 4; kb++) {
            bf16x8 bfr = as_bf16x8(bp[kb * 64 + lane]);
            acc = __builtin_amdgcn_mfma_f32_16x16x32_bf16(afr[kb], bfr, acc, 0, 0, 0);
        }
        int col = c * 16 + (lane & 15);
        float bias = bcat[(t * NMAT + m) * ND + col];
        int rbase = rt * 16 + (lane >> 4) * 4;
        #pragma unroll
        for (int r = 0; r < 4; r++) {
            int grow = rbase + r;
            if (grow >= cnt) continue;
            int node = nodes[grow];
            ushort_t val = f2bf(acc[r] + bias);
            if (m == 0)       out_qn[(size_t)node * ND + col] = val;
            else if (m <= 4)  out_kt[((size_t)node * NR + (m - 1)) * ND + col] = val;
            else if (m == 5)  out_v1[(size_t)node * ND + col] = val;
            else              out_vt[((size_t)node * NR + (m - 6)) * ND + col] = val;
        }
    }
}

// Fused logits + online segment softmax, wave per target node.
// lane = (edge-slot, head): 8 edges per iteration, no per-edge shuffles.
__global__ void __launch_bounds__(256) k_attmd(
    int n, const int* off, const int* srp, const int* ntype,
    const ushort_t* qn, const ushort_t* kt, const float* r_pri,
    float* atts, ushort_t* mb, float* db)
{
    int wv = threadIdx.x >> 6, lane = threadIdx.x & 63;
    int i = blockIdx.x * 4 + wv;
    if (i >= n) return;
    int h = lane & 7, slot = lane >> 3;
    int tt = ntype[i];
    float qf[16];
    load_bf8(qn + (size_t)i * ND + h * DKK, qf);
    load_bf8(qn + (size_t)i * ND + h * DKK + 8, qf + 8);
    const float* prib = r_pri + (size_t)(tt * NR * NT) * NH + h;
    int d0 = off[i], d1 = off[i + 1];
    float m = -3.0e38f, den = 0.f;
    #pragma unroll 2
    for (int p0 = d0; p0 < d1; p0 += 8) {
        int p = p0 + slot;
        bool live = (p < d1);
        int sp = live ? srp[p] : 0;
        int sr = sp & 0x0fffffff;            // src*NR + r
        int st = ((unsigned int)sp) >> 28;   // ntype[src]
        int r = sr & (NR - 1);
        float kf[16];
        const ushort_t* kp = kt + (size_t)sr * ND + h * DKK;
        load_bf8(kp, kf);
        load_bf8(kp + 8, kf + 8);
        float a = 0.f;
        #pragma unroll
        for (int f = 0; f < 16; f++) a += qf[f] * kf[f];
        float pri = prib[(r * NT + st) * NH];
        float logit = fminf(fmaxf(a * pri * 0.25f, -1.0e4f), 1.0e4f);  // NaN scrub
        if (live) {
            atts[(size_t)p * NH + h] = logit;                           // coalesced 256B
            float mnew = fmaxf(m, logit);
            den = den * expf(m - mnew) + expf(logit - mnew);
            m = mnew;
        }
    }
    // combine the 8 edge-slot partials per head (xor 8,16,32)
    #pragma unroll
    for (int d = 8; d < 64; d <<= 1) {
        float mo = __shfl_xor(m, d, 64);
        float dn = __shfl_xor(den, d, 64);
        float mnew = fmaxf(m, mo);
        den = den * expf(m - mnew) + dn * expf(mo - mnew);
        m = mnew;
    }
    if (slot == 0) {
        ushort_t mh = (d1 > d0) ? f2bf(m) : (ushort_t)0;
        float dfin = (d1 > d0) ? den * expf(m - bf2f(mh)) : 0.f;
        mb[i * NH + h] = mh;
        db[i * NH + h] = dfin;
    }
}

// wave-per-node aggregation; softmax normalize folded in; srp+atts read sequentially
__global__ void __launch_bounds__(256) k_aggr_fast(
    int n, const int* off, const int* srp, const ushort_t* vt, const float* atts,
    const ushort_t* mb, const float* db, float* aggr)
{
    int wv = threadIdx.x >> 6, lane = threadIdx.x & 63;
    int i = blockIdx.x * 4 + wv;
    if (i >= n) return;
    int h = lane >> 3;
    float mref = bf2f(mb[i * NH + h]);
    float inv = 1.f / (db[i * NH + h] + 1e-16f);
    int d0 = off[i], d1 = off[i + 1];
    float acc0 = 0.f, acc1 = 0.f;
    #pragma unroll 4
    for (int p = d0; p < d1; p++) {
        int sr = srp[p] & 0x0fffffff;
        float w = expf(atts[(size_t)p * NH + h] - mref) * inv;
        unsigned int u = *reinterpret_cast<const unsigned int*>(
            vt + (size_t)sr * ND + lane * 2);
        acc0 += w * bf2f(u & 0xffff);
        acc1 += w * bf2f(u >> 16);
    }
    float2 o; o.x = acc0; o.y = acc1;
    *reinterpret_cast<float2*>(aggr + (size_t)i * ND + lane * 2) = o;
}

// ================= FALLBACK PATH (round-3 proven kernels) =================

__global__ void k_proj(int n, const float* x_in, const int* ntype, const int* order,
                       const float* Kw, const float* Kb,
                       const float* Qw, const float* Qb,
                       const float* Vw, const float* Vb,
                       ushort_t* kn, ushort_t* qn, ushort_t* vn, ushort_t* v1) {
    __shared__ float xs[NB][ND];
    __shared__ int nodes[NB];
    __shared__ int types[NB];
    int tid = threadIdx.x;
    int base = blockIdx.x * NB;
    int cnt = min(NB, n - base);
    if (tid < cnt) { int nd = order[base + tid]; nodes[tid] = nd; types[tid] = ntype[nd]; }
    __syncthreads();
    for (int j = 0; j < cnt; j++) xs[j][tid] = x_in[(size_t)nodes[j] * ND + tid];
    __syncthreads();
    bool uni = (types[0] == types[cnt - 1]);
    for (int m = 0; m < 4; m++) {
        const float *W, *B; ushort_t* out; int forced_t = -1;
        if (m == 0)      { W = Kw; B = Kb; out = kn; }
        else if (m == 1) { W = Qw; B = Qb; out = qn; }
        else if (m == 2) { W = Vw; B = Vb; out = vn; }
        else             { W = Vw; B = Vb; out = v1; forced_t = 1; }
        if (uni || forced_t >= 0) {
            int t = (forced_t >= 0) ? forced_t : types[0];
            float bias = B[t * ND + tid];
            float acc[NB];
            #pragma unroll
            for (int j = 0; j < NB; j++) acc[j] = bias;
            const float* Wp = W + (size_t)t * ND * ND + tid;
            for (int d = 0; d < ND; d++) {
                float w = Wp[(size_t)d * ND];
                #pragma unroll
                for (int j = 0; j < NB; j++) acc[j] += xs[j][d] * w;
            }
            for (int j = 0; j < cnt; j++) out[(size_t)nodes[j] * ND + tid] = f2bf(acc[j]);
        } else {
            for (int j = 0; j < cnt; j++) {
                int t = types[j];
                float acc = B[t * ND + tid];
                const float* Wp = W + (size_t)t * ND * ND + tid;
                for (int d = 0; d < ND; d++) acc += xs[j][d] * Wp[(size_t)d * ND];
                out[(size_t)nodes[j] * ND + tid] = f2bf(acc);
            }
        }
    }
}

__global__ void k_att(int e, const int* src, const int* tgt, const int* etype, const int* ntype,
                      const ushort_t* kn, const ushort_t* qn,
                      const float* r_att, const float* r_pri, float* att) {
    int id = blockIdx.x * 256 + threadIdx.x;
    if (id >= e * NH) return;
    int ee = id >> 3, h = id & 7;
    int s = src[ee], t = tgt[ee], r = etype[ee];
    float kf[16], qf[16];
    load_bf8(kn + (size_t)s * ND + h * DKK, kf);
    load_bf8(kn + (size_t)s * ND + h * DKK + 8, kf + 8);
    load_bf8(qn + (size_t)t * ND + h * DKK, qf);
    load_bf8(qn + (size_t)t * ND + h * DKK + 8, qf + 8);
    const float* W = r_att + (size_t)(r * NH + h) * DKK * DKK;
    float kt[16];
    #pragma unroll
    for (int f = 0; f < 16; f++) kt[f] = 0.f;
    #pragma unroll 4
    for (int d = 0; d < 16; d++) {
        float kd = kf[d];
        #pragma unroll
        for (int f = 0; f < 16; f++) kt[f] += kd * W[d * 16 + f];
    }
    float a = 0.f;
    #pragma unroll
    for (int f = 0; f < 16; f++) a += qf[f] * kt[f];
    int tt = ntype[t], st = ntype[s];
    float pri = r_pri[((tt * NR + r) * NT + st) * NH + h];
    float logit = a * pri * 0.25f;
    logit = fminf(fmaxf(logit, -1.0e4f), 1.0e4f);
    att[(size_t)ee * NH + h] = logit;
}

__global__ void k_mden(int n, const int* off, const int* sorted,
                       const float* att, ushort_t* mb, float* db) {
    int id = blockIdx.x * 256 + threadIdx.x;
    if (id >= n * NH) return;
    int i = id >> 3, h = id & 7;
    int d0 = off[i], d1 = off[i + 1];
    float m = -3.0e38f;
    for (int p = d0; p < d1; p++) m = fmaxf(m, att[(size_t)sorted[p] * NH + h]);
    ushort_t mh = (d1 > d0) ? f2bf(m) : (ushort_t)0;
    float mref = bf2f(mh);
    float den = 0.f;
    for (int p = d0; p < d1; p++) den += expf(att[(size_t)sorted[p] * NH + h] - mref);
    mb[id] = mh;
    db[id] = den;
}

__global__ void k_norm(int e, const int* tgt, const ushort_t* mb, const float* db, float* att) {
    int id = blockIdx.x * 256 + threadIdx.x;
    if (id >= e * NH) return;
    int ee = id >> 3, h = id & 7;
    int t = tgt[ee];
    float w = expf(att[id] - bf2f(mb[t * NH + h])) / (db[t * NH + h] + 1e-16f);
    att[id] = w;
}

__global__ void k_aggr(int n, const int* off, const int* sorted, const int* src, const int* etype,
                       const ushort_t* vn, const float* r_msg, const float* att, float* aggr) {
    int wv = threadIdx.x >> 6, lane = threadIdx.x & 63;
    int i = blockIdx.x * 4 + wv;
    if (i >= n) return;
    int h = lane >> 3, f0 = (lane & 7) * 2;
    int d0 = off[i], d1 = off[i + 1];
    float acc0 = 0.f, acc1 = 0.f;
    for (int p = d0; p < d1; p++) {
        int ee = sorted[p];
        int s = src[ee], r = etype[ee];
        float w = att[(size_t)ee * NH + h];
        float vj[16];
        load_bf8(vn + (size_t)s * ND + h * DKK, vj);
        load_bf8(vn + (size_t)s * ND + h * DKK + 8, vj + 8);
        const float* Wm = r_msg + (size_t)(r * NH + h) * DKK * DKK + f0;
        float a0 = 0.f, a1 = 0.f;
        #pragma unroll
        for (int d = 0; d < 16; d++) {
            a0 += vj[d] * Wm[d * 16];
            a1 += vj[d] * Wm[d * 16 + 1];
        }
        acc0 += w * a0; acc1 += w * a1;
    }
    aggr[(size_t)i * ND + h * DKK + f0]     = acc0;
    aggr[(size_t)i * ND + h * DKK + f0 + 1] = acc1;
}

// ---------------- shared epilogue ----------------

__global__ void k_spk(int n, const int* winner, const int* tgt, const ushort_t* v1,
                      const float* s2u, float* aggr) {
    __shared__ float xs[NB][ND];
    __shared__ int wn[NB];
    int tid = threadIdx.x;
    int base = blockIdx.x * NB;
    int cnt = min(NB, n - base);
    if (tid < cnt) wn[tid] = winner[base + tid];
    __syncthreads();
    for (int j = 0; j < cnt; j++) {
        int w = wn[j];
        xs[j][tid] = (w >= 0) ? bf2f(v1[(size_t)tgt[w] * ND + tid]) : 0.f;
    }
    __syncthreads();
    float acc[NB];
    #pragma unroll
    for (int j = 0; j < NB; j++) acc[j] = 0.f;
    const float* Wp = s2u + tid;
    for (int d = 0; d < ND; d++) {
        float w = Wp[(size_t)d * ND];
        #pragma unroll
        for (int j = 0; j < NB; j++) acc[j] += xs[j][d] * w;
    }
    for (int j = 0; j < cnt; j++) {
        size_t idx = (size_t)(base + j) * ND + tid;
        float g = aggr[idx] + acc[j];
        g = 0.5f * g * (1.f + erff(g * 0.70710678118f));
        aggr[idx] = g;
    }
}

__global__ void k_final(int n, const float* x_in, const int* ntype, const int* order,
                        const float* Aw, const float* Ab, const float* skip,
                        const float* aggr, float* out) {
    __shared__ float xs[NB][ND];
    __shared__ int nodes[NB];
    __shared__ int types[NB];
    int tid = threadIdx.x;
    int base = blockIdx.x * NB;
    int cnt = min(NB, n - base);
    if (tid < cnt) { int nd = order[base + tid]; nodes[tid] = nd; types[tid] = ntype[nd]; }
    __syncthreads();
    for (int j = 0; j < cnt; j++) xs[j][tid] = aggr[(size_t)nodes[j] * ND + tid];
    __syncthreads();
    bool uni = (types[0] == types[cnt - 1]);
    if (uni) {
        int t = types[0];
        float bias = Ab[t * ND + tid];
        float acc[NB];
        #pragma unroll
        for (int j = 0; j < NB; j++) acc[j] = bias;
        const float* Wp = Aw + (size_t)t * ND * ND + tid;
        for (int d = 0; d < ND; d++) {
            float w = Wp[(size_t)d * ND];
            #pragma unroll
            for (int j = 0; j < NB; j++) acc[j] += xs[j][d] * w;
        }
        float alpha = 1.f / (1.f + expf(-skip[t]));
        for (int j = 0; j < cnt; j++) {
            float xin = x_in[(size_t)nodes[j] * ND + tid];
            out[(size_t)nodes[j] * ND + tid] = acc[j] * alpha + xin * (1.f - alpha);
        }
    } else {
        for (int j = 0; j < cnt; j++) {
            int t = types[j];
            float acc = Ab[t * ND + tid];
            const float* Wp = Aw + (size_t)t * ND * ND + tid;
            for (int d = 0; d < ND; d++) acc += xs[j][d] * Wp[(size_t)d * ND];
            float alpha = 1.f / (1.f + expf(-skip[t]));
            float xin = x_in[(size_t)nodes[j] * ND + tid];
            out[(size_t)nodes[j] * ND + tid] = acc * alpha + xin * (1.f - alpha);
        }
    }
}

extern "C" void kernel_launch(void* const* d_in, const int* in_sizes, int n_in,
                              void* d_out, int out_size, void* d_ws, size_t ws_size,
                              hipStream_t stream) {
    const float* node_inp = (const float*)d_in[0];
    const int* node_type  = (const int*)d_in[1];
    const int* edge_index = (const int*)d_in[2];
    const int* edge_type  = (const int*)d_in[3];
    const float* Kw = (const float*)d_in[5];
    const float* Kb = (const float*)d_in[6];
    const float* Qw = (const float*)d_in[7];
    const float* Qb = (const float*)d_in[8];
    const float* Vw = (const float*)d_in[9];
    const float* Vb = (const float*)d_in[10];
    const float* Aw = (const float*)d_in[11];
    const float* Ab = (const float*)d_in[12];
    const float* r_pri = (const float*)d_in[13];
    const float* r_att = (const float*)d_in[14];
    const float* r_msg = (const float*)d_in[15];
    const float* s2u   = (const float*)d_in[16];
    const float* skip  = (const float*)d_in[17];

    int n = in_sizes[1];
    int e = in_sizes[3];
    const int* srcp = edge_index;
    const int* tgtp = edge_index + e;

    char* wsp = (char*)d_ws;
    size_t woff = 0;
    auto alloc = [&](size_t b) { void* p = wsp + woff; woff += (b + 255) & ~(size_t)255; return p; };

    // ---- common infra ----
    int* offs     = (int*)alloc((size_t)(n + 1) * 4);
    int* nxt      = (int*)alloc((size_t)n * 4);
    int* winner   = (int*)alloc((size_t)n * 4);
    int* order    = (int*)alloc((size_t)n * 4);
    int* tcnt     = (int*)alloc(16);
    int* tnext    = (int*)alloc(16);
    int* tstart   = (int*)alloc(16);
    int* eord     = (int*)alloc((size_t)e * 4);   // fast: srp record; fallback: sorted edge id
    ushort_t* mb  = (ushort_t*)alloc((size_t)n * NH * 2);
    float* db     = (float*)alloc((size_t)n * NH * 4);
    ushort_t* v1b = (ushort_t*)alloc((size_t)n * ND * 2);
    float* att    = (float*)alloc((size_t)e * NH * 4);
    size_t commonEnd = woff;

    // ---- fast-path extra layout ----
    ushort_t* Kcomb = (ushort_t*)alloc((size_t)NT * NR * ND * ND * 2);
    ushort_t* Vcomb = (ushort_t*)alloc((size_t)NT * NR * ND * ND * 2);
    float* kbc      = (float*)alloc((size_t)NT * NR * ND * 4);
    float* vbc      = (float*)alloc((size_t)NT * NR * ND * 4);
    ushort_t* Wall  = (ushort_t*)alloc((size_t)NT * NMAT * 8 * 4 * 512 * 2);
    float* bcat     = (float*)alloc((size_t)NT * NMAT * ND * 4);
    char* F         = (char*)alloc((size_t)n * 1536);   // phase1: qn+kt; phase2: vt+aggr
    size_t fastEnd = woff;

    int gn = (n + 255) / 256;
    int ge = (e + 255) / 256;
    int fast = (ws_size >= fastEnd) ? 1 : 0;

    k_zero<<<gn, 256, 0, stream>>>(n, offs, winner, tcnt);
    k_count<<<ge, 256, 0, stream>>>(n, e, srcp, tgtp, edge_type, node_type, offs, winner, tcnt);
    k_scan<<<1, 1024, 0, stream>>>(n, offs, nxt, tcnt, tnext, tstart);
    k_scatter<<<ge, 256, 0, stream>>>(n, e, srcp, tgtp, edge_type, node_type, nxt,
                                      eord, fast, tnext, order);

    if (fast) {
        // ======== FAST PATH ========
        ushort_t* qn  = (ushort_t*)F;
        ushort_t* kt  = (ushort_t*)(F + (size_t)n * 256);
        ushort_t* vt  = (ushort_t*)F;                         // overlays qn+kt (dead after k_attmd)
        float* aggr   = (float*)(F + (size_t)n * 1024);       // overlays kt tail (dead)
        int gproj = (n + 31) / 32 + NT;                       // upper bound on padded tiles

        k_comb<<<2 * NT * NR, 128, 0, stream>>>(Kw, Kb, r_att, Vw, Vb, r_msg,
                                                Kcomb, kbc, Vcomb, vbc);
        k_pack<<<NT * NMAT * 8 * 4, 64, 0, stream>>>(Qw, Qb, Vw, Vb, Kcomb, kbc,
                                                     Vcomb, vbc, Wall, bcat);
        // phase1: mats 0..5 -> qn, kt, v1b
        k_projm<<<gproj, 256, 0, stream>>>(n, node_inp, order, tcnt, tstart, Wall, bcat,
                                           0, 6, qn, kt, v1b, (ushort_t*)nullptr);
        // fused logits + online softmax (8 edges/iteration, sorted-order logits)
        k_attmd<<<(n + 3) / 4, 256, 0, stream>>>(n, offs, eord, node_type,
                                                 qn, kt, r_pri, att, mb, db);
        // phase2: mats 6..9 -> vt (overlays qn/kt)
        k_projm<<<gproj, 256, 0, stream>>>(n, node_inp, order, tcnt, tstart, Wall, bcat,
                                           6, 4, (ushort_t*)nullptr, (ushort_t*)nullptr,
                                           (ushort_t*)nullptr, vt);
        k_aggr_fast<<<(n + 3) / 4, 256, 0, stream>>>(n, offs, eord, vt, att, mb, db, aggr);
        k_spk<<<(n + NB - 1) / NB, 128, 0, stream>>>(n, winner, tgtp, v1b, s2u, aggr);
        k_final<<<(n + NB - 1) / NB, 128, 0, stream>>>(n, node_inp, node_type, order,
                                                       Aw, Ab, skip, aggr, (float*)d_out);
    } else {
        // ======== FALLBACK (round-3 layout, proven) ========
        woff = commonEnd;
        ushort_t* vn  = (ushort_t*)alloc((size_t)n * ND * 2);
        char* regA    = (char*)alloc((size_t)n * ND * 2 * 2);
        ushort_t* kn  = (ushort_t*)regA;
        ushort_t* qn  = (ushort_t*)(regA + (size_t)n * ND * 2);
        float* aggr   = (float*)regA;

        k_proj<<<(n + NB - 1) / NB, 128, 0, stream>>>(n, node_inp, node_type, order,
                                                      Kw, Kb, Qw, Qb, Vw, Vb, kn, qn, vn, v1b);
        k_att<<<(e * NH + 255) / 256, 256, 0, stream>>>(e, srcp, tgtp, edge_type, node_type,
                                                        kn, qn, r_att, r_pri, att);
        k_mden<<<(n * NH + 255) / 256, 256, 0, stream>>>(n, offs, eord, att, mb, db);
        k_norm<<<(e * NH + 255) / 256, 256, 0, stream>>>(e, tgtp, mb, db, att);
        k_aggr<<<(n + 3) / 4, 256, 0, stream>>>(n, offs, eord, srcp, edge_type, vn, r_msg, att, aggr);
        k_spk<<<(n + NB - 1) / NB, 128, 0, stream>>>(n, winner, tgtp, v1b, s2u, aggr);
        k_final<<<(n + NB - 1) / NB, 128, 0, stream>>>(n, node_inp, node_type, order,
                                                       Aw, Ab, skip, aggr, (float*)d_out);
    }
}

// Round 10
// 473.105 us; speedup vs baseline: 1.4200x; 1.1669x over previous
//
#include <hip/hip_runtime.h>
#include <hip/hip_bf16.h>
#include <math.h>

#define ND 128
#define NH 8
#define DKK 16
#define NT 3
#define NR 4
#define NB 8
#define NMAT 10   // packed mats: 0=Q, 1..4=Kcomb[r], 5=V(type1), 6..9=Vcomb[r]
#define SCB 4096  // scan elems per block (256 threads x 16)

typedef unsigned short ushort_t;
typedef __bf16 bf16_t;
typedef bf16_t bf16x8 __attribute__((ext_vector_type(8)));
typedef float f32x4 __attribute__((ext_vector_type(4)));

__device__ __forceinline__ float bf2f(unsigned short u) {
    union { unsigned int i; float f; } v; v.i = ((unsigned int)u) << 16; return v.f;
}
__device__ __forceinline__ unsigned short f2bf(float f) {
    union { float f; unsigned int i; } v; v.f = f;
    unsigned int x = v.i;
    unsigned int lsb = (x >> 16) & 1u;
    x += 0x7fffu + lsb;
    return (unsigned short)(x >> 16);
}
__device__ __forceinline__ unsigned int pk2(float a, float b) {
    return (unsigned int)f2bf(a) | ((unsigned int)f2bf(b) << 16);
}
__device__ __forceinline__ void load_bf8(const ushort_t* p, float* o) {
    uint4 u = *reinterpret_cast<const uint4*>(p);
    o[0]=bf2f(u.x & 0xffff); o[1]=bf2f(u.x >> 16);
    o[2]=bf2f(u.y & 0xffff); o[3]=bf2f(u.y >> 16);
    o[4]=bf2f(u.z & 0xffff); o[5]=bf2f(u.z >> 16);
    o[6]=bf2f(u.w & 0xffff); o[7]=bf2f(u.w >> 16);
}
__device__ __forceinline__ bf16x8 as_bf16x8(uint4 u) {
    union { uint4 u; bf16x8 v; } c; c.u = u; return c.v;
}

// ---------------- sort / bucket infrastructure ----------------

__global__ void k_zero(int n, int* offs, int* winner, int* tcnt) {
    int i = blockIdx.x * 256 + threadIdx.x;
    if (i < n) { offs[i] = 0; winner[i] = -1; }
    if (i < NT) tcnt[i] = 0;
}

// wave-aggregated 3-bin atomics
__global__ void k_count(int n, int e, const int* src, const int* tgt, const int* etype,
                        const int* ntype, int* offs, int* winner, int* tcnt) {
    int i = blockIdx.x * 256 + threadIdx.x;
    if (i < e) {
        atomicAdd(&offs[tgt[i]], 1);
        if (etype[i] == 0) atomicMax(&winner[src[i]], i);  // numpy last-write-wins == max edge id
    }
    if (i < n) {
        int t = ntype[i];
        int lane = threadIdx.x & 63;
        #pragma unroll
        for (int tt = 0; tt < NT; tt++) {
            bool me = (t == tt);
            unsigned long long m = __ballot(me);
            if (me) {
                int lower = __popcll(m & ((1ull << lane) - 1ull));
                if (lower == 0) atomicAdd(&tcnt[tt], __popcll(m));
            }
        }
    }
}

// ---- multi-block exclusive scan (3 phases, each tiny) ----

__global__ void k_scanA(int n, const int* offs, int* bsum) {
    __shared__ int red[256];
    int b = blockIdx.x, tid = threadIdx.x;
    int base = b * SCB + tid * 16;
    int s = 0;
    #pragma unroll
    for (int i = 0; i < 16; i++) {
        int idx = base + i;
        if (idx < n) s += offs[idx];
    }
    red[tid] = s;
    __syncthreads();
    for (int d = 128; d > 0; d >>= 1) {
        if (tid < d) red[tid] += red[tid + d];
        __syncthreads();
    }
    if (tid == 0) bsum[b] = red[0];
}

__global__ void k_scanB(int nb, const int* bsum, int* boff,
                        const int* tcnt, int* tnext, int* tstart) {
    if (threadIdx.x == 0) {
        int run = 0;
        for (int b = 0; b < nb; b++) { boff[b] = run; run += bsum[b]; }
        int t0 = 0;
        for (int t = 0; t < NT; t++) { tnext[t] = t0; tstart[t] = t0; t0 += tcnt[t]; }
    }
}

__global__ void k_scanC(int n, int* offs, int* next, const int* boff) {
    __shared__ int red[256];
    int b = blockIdx.x, tid = threadIdx.x;
    int base = b * SCB + tid * 16;
    int v[16];
    int s = 0;
    #pragma unroll
    for (int i = 0; i < 16; i++) {
        int idx = base + i;
        v[i] = (idx < n) ? offs[idx] : 0;
        s += v[i];
    }
    red[tid] = s;
    __syncthreads();
    for (int d = 1; d < 256; d <<= 1) {
        int vv = (tid >= d) ? red[tid - d] : 0;
        __syncthreads();
        red[tid] += vv;
        __syncthreads();
    }
    int run = boff[b] + red[tid] - s;   // exclusive prefix for this thread
    #pragma unroll
    for (int i = 0; i < 16; i++) {
        int idx = base + i;
        if (idx < n) { offs[idx] = run; next[idx] = run; run += v[i]; }
    }
    if (base <= n && n < base + 16) offs[n] = run;   // grand total
}

// mode=1 (fast): eord[p] = (src*NR+etype) | ntype[src]<<28 ; mode=0: eord[p] = edge id
__global__ void k_scatter(int n, int e, const int* src, const int* tgt, const int* etype,
                          const int* ntype, int* next, int* eord, int mode,
                          int* tnext, int* order) {
    int i = blockIdx.x * 256 + threadIdx.x;
    if (i < e) {
        int p = atomicAdd(&next[tgt[i]], 1);
        if (mode) {
            int s = src[i];
            eord[p] = (s * NR + etype[i]) | (ntype[s] << 28);
        } else {
            eord[p] = i;
        }
    }
    if (i < n) {
        int t = ntype[i];
        int lane = threadIdx.x & 63;
        #pragma unroll
        for (int tt = 0; tt < NT; tt++) {
            bool me = (t == tt);
            unsigned long long m = __ballot(me);
            if (me) {
                int lower = __popcll(m & ((1ull << lane) - 1ull));
                int leader = __ffsll((long long)m) - 1;
                int base = 0;
                if (lane == leader) base = atomicAdd(&tnext[tt], __popcll(m));
                base = __shfl(base, leader, 64);
                order[base + lower] = i;
            }
        }
    }
}

// ================= FAST PATH =================

// Combined weights: Kcomb[t,r][d][h*16+f] = sum_j Kw[t][d][16h+j] * Watt[r][h][j][f]
__global__ void k_comb(const float* Kw, const float* Kb, const float* r_att,
                       const float* Vw, const float* Vb, const float* r_msg,
                       ushort_t* Kcomb, float* kbc, ushort_t* Vcomb, float* vbc) {
    int kind = blockIdx.x / (NT * NR);
    int tr = blockIdx.x % (NT * NR);
    int t = tr / NR, r = tr % NR;
    const float* W0 = kind ? Vw : Kw;
    const float* B0 = kind ? Vb : Kb;
    const float* Wr = kind ? r_msg : r_att;
    ushort_t* outW = kind ? Vcomb : Kcomb;
    float* outB = kind ? vbc : kbc;
    int tid = threadIdx.x;           // 128 = (h,f)
    int h = tid >> 4, f = tid & 15;
    float wcol[16];
    #pragma unroll
    for (int j = 0; j < 16; j++) wcol[j] = Wr[(((size_t)r * NH + h) * DKK + j) * DKK + f];
    __shared__ float row[ND];
    for (int d = 0; d < ND; d++) {
        __syncthreads();
        row[tid] = W0[((size_t)t * ND + d) * ND + tid];
        __syncthreads();
        float s = 0.f;
        #pragma unroll
        for (int j = 0; j < 16; j++) s += row[h * DKK + j] * wcol[j];
        outW[((size_t)tr * ND + d) * ND + tid] = f2bf(s);
    }
    float sb = 0.f;
    #pragma unroll
    for (int j = 0; j < 16; j++) sb += B0[t * ND + h * DKK + j] * wcol[j];
    outB[tr * ND + tid] = sb;
}

// pack all 10 per-type weight matrices into MFMA B-fragment order + biases
__global__ void k_pack(const float* Qw, const float* Qb, const float* Vw, const float* Vb,
                       const ushort_t* Kcomb, const float* kbc,
                       const ushort_t* Vcomb, const float* vbc,
                       ushort_t* Wall, float* bcat) {
    int blk = blockIdx.x;
    int kb = blk & 3;
    int c = (blk >> 2) & 7;
    int tm = blk >> 5;
    int m = tm % NMAT, t = tm / NMAT;
    int lane = threadIdx.x;
    int nn = c * 16 + (lane & 15);
    int quad = lane >> 4;
    ushort_t* dst = Wall + (size_t)blk * 512 + lane * 8;
    #pragma unroll
    for (int j = 0; j < 8; j++) {
        int k = kb * 32 + quad * 8 + j;
        float w;
        if (m == 0)      w = Qw[((size_t)t * ND + k) * ND + nn];
        else if (m <= 4) w = bf2f(Kcomb[((size_t)(t * NR + m - 1) * ND + k) * ND + nn]);
        else if (m == 5) w = Vw[((size_t)(ND + k)) * ND + nn];   // type-1 V
        else             w = bf2f(Vcomb[((size_t)(t * NR + m - 6) * ND + k) * ND + nn]);
        dst[j] = f2bf(w);
    }
    if (kb == 0 && quad == 0) {
        float b;
        if (m == 0)      b = Qb[t * ND + nn];
        else if (m <= 4) b = kbc[(t * NR + m - 1) * ND + nn];
        else if (m == 5) b = Vb[ND + nn];
        else             b = vbc[(t * NR + m - 6) * ND + nn];
        bcat[(t * NMAT + m) * ND + nn] = b;
    }
}

// MFMA projection: every block is type-uniform by construction (padded type segments)
__global__ void __launch_bounds__(256) k_projm(
    int n, const float* x_in, const int* order,
    const int* tcnt, const int* tstart,
    const ushort_t* Wall, const float* bcat,
    int m0, int nm,
    ushort_t* out_qn, ushort_t* out_kt, ushort_t* out_v1, ushort_t* out_vt)
{
    __shared__ __align__(16) ushort_t xs[4096];  // A-fragment-permuted bf16: [rt][kb][lane][8]
    __shared__ int nodes[32];
    // block -> (type, local tile)
    int b = blockIdx.x;
    int nb0 = (tcnt[0] + 31) >> 5, nb1 = (tcnt[1] + 31) >> 5, nb2 = (tcnt[2] + 31) >> 5;
    int t, lb;
    if (b < nb0)                  { t = 0; lb = b; }
    else if (b < nb0 + nb1)       { t = 1; lb = b - nb0; }
    else if (b < nb0 + nb1 + nb2) { t = 2; lb = b - nb0 - nb1; }
    else return;
    int segoff = lb * 32;
    int cnt = min(32, tcnt[t] - segoff);
    int segbase = tstart[t] + segoff;
    int tid = threadIdx.x;
    if (tid < 32) nodes[tid] = (tid < cnt) ? order[segbase + tid] : -1;
    __syncthreads();
    // stage x -> permuted bf16, two contiguous 16B writes per thread (conflict-free)
    {
        int row = tid >> 3;
        int d0 = (tid & 7) * 16;
        int rt = row >> 4, rl = row & 15;
        int kb = d0 >> 5, q0 = (d0 >> 3) & 3;
        uint4 c0, c1;
        if (row < cnt) {
            const float4* xp4 = (const float4*)(x_in + (size_t)nodes[row] * ND + d0);
            float4 a = xp4[0], b2 = xp4[1], c2 = xp4[2], d4 = xp4[3];
            c0.x = pk2(a.x, a.y);   c0.y = pk2(a.z, a.w);
            c0.z = pk2(b2.x, b2.y); c0.w = pk2(b2.z, b2.w);
            c1.x = pk2(c2.x, c2.y); c1.y = pk2(c2.z, c2.w);
            c1.z = pk2(d4.x, d4.y); c1.w = pk2(d4.z, d4.w);
        } else {
            c0.x = c0.y = c0.z = c0.w = 0u;
            c1 = c0;
        }
        *(uint4*)&xs[((rt * 4 + kb) * 64 + q0 * 16 + rl) * 8]       = c0;
        *(uint4*)&xs[((rt * 4 + kb) * 64 + (q0 + 1) * 16 + rl) * 8] = c1;
    }
    __syncthreads();

    int w = tid >> 6, lane = tid & 63;
    int rt = w & 1;                      // wave's row-tile (16 nodes)
    bf16x8 afr[4];
    #pragma unroll
    for (int kb = 0; kb < 4; kb++)
        afr[kb] = as_bf16x8(*(const uint4*)&xs[((rt * 4 + kb) * 64 + lane) * 8]);
    int nct = nm * 8;
    for (int ct = (w >> 1); ct < nct; ct += 2) {
        int m = m0 + (ct >> 3), c = ct & 7;
        const uint4* bp = (const uint4*)(Wall + ((((size_t)t * NMAT + m) * 8 + c) * 4) * 512);
        f32x4 acc = {0.f, 0.f, 0.f, 0.f};
        #pragma unroll
        for (int kb = 0; kb < 4; kb++) {
            bf16x8 bfr = as_bf16x8(bp[kb * 64 + lane]);
            acc = __builtin_amdgcn_mfma_f32_16x16x32_bf16(afr[kb], bfr, acc, 0, 0, 0);
        }
        int col = c * 16 + (lane & 15);
        float bias = bcat[(t * NMAT + m) * ND + col];
        int rbase = rt * 16 + (lane >> 4) * 4;
        #pragma unroll
        for (int r = 0; r < 4; r++) {
            int grow = rbase + r;
            if (grow >= cnt) continue;
            int node = nodes[grow];
            ushort_t val = f2bf(acc[r] + bias);
            if (m == 0)       out_qn[(size_t)node * ND + col] = val;
            else if (m <= 4)  out_kt[((size_t)node * NR + (m - 1)) * ND + col] = val;
            else if (m == 5)  out_v1[(size_t)node * ND + col] = val;
            else              out_vt[((size_t)node * NR + (m - 6)) * ND + col] = val;
        }
    }
}

// Fused logits + online segment softmax, wave per target node.
// lane = (edge-slot, head): 8 edges per iteration, no per-edge shuffles.
__global__ void __launch_bounds__(256) k_attmd(
    int n, const int* off, const int* srp, const int* ntype,
    const ushort_t* qn, const ushort_t* kt, const float* r_pri,
    float* atts, ushort_t* mb, float* db)
{
    int wv = threadIdx.x >> 6, lane = threadIdx.x & 63;
    int i = blockIdx.x * 4 + wv;
    if (i >= n) return;
    int h = lane & 7, slot = lane >> 3;
    int tt = ntype[i];
    float qf[16];
    load_bf8(qn + (size_t)i * ND + h * DKK, qf);
    load_bf8(qn + (size_t)i * ND + h * DKK + 8, qf + 8);
    const float* prib = r_pri + (size_t)(tt * NR * NT) * NH + h;
    int d0 = off[i], d1 = off[i + 1];
    float m = -3.0e38f, den = 0.f;
    #pragma unroll 2
    for (int p0 = d0; p0 < d1; p0 += 8) {
        int p = p0 + slot;
        bool live = (p < d1);
        int sp = live ? srp[p] : 0;
        int sr = sp & 0x0fffffff;            // src*NR + r
        int st = ((unsigned int)sp) >> 28;   // ntype[src]
        int r = sr & (NR - 1);
        float kf[16];
        const ushort_t* kp = kt + (size_t)sr * ND + h * DKK;
        load_bf8(kp, kf);
        load_bf8(kp + 8, kf + 8);
        float a = 0.f;
        #pragma unroll
        for (int f = 0; f < 16; f++) a += qf[f] * kf[f];
        float pri = prib[(r * NT + st) * NH];
        float logit = fminf(fmaxf(a * pri * 0.25f, -1.0e4f), 1.0e4f);  // NaN scrub
        if (live) {
            atts[(size_t)p * NH + h] = logit;                           // coalesced 256B
            float mnew = fmaxf(m, logit);
            den = den * expf(m - mnew) + expf(logit - mnew);
            m = mnew;
        }
    }
    // combine the 8 edge-slot partials per head (xor 8,16,32)
    #pragma unroll
    for (int d = 8; d < 64; d <<= 1) {
        float mo = __shfl_xor(m, d, 64);
        float dn = __shfl_xor(den, d, 64);
        float mnew = fmaxf(m, mo);
        den = den * expf(m - mnew) + dn * expf(mo - mnew);
        m = mnew;
    }
    if (slot == 0) {
        ushort_t mh = (d1 > d0) ? f2bf(m) : (ushort_t)0;
        float dfin = (d1 > d0) ? den * expf(m - bf2f(mh)) : 0.f;
        mb[i * NH + h] = mh;
        db[i * NH + h] = dfin;
    }
}

// wave-per-node aggregation; softmax normalize folded in; srp+atts read sequentially
__global__ void __launch_bounds__(256) k_aggr_fast(
    int n, const int* off, const int* srp, const ushort_t* vt, const float* atts,
    const ushort_t* mb, const float* db, float* aggr)
{
    int wv = threadIdx.x >> 6, lane = threadIdx.x & 63;
    int i = blockIdx.x * 4 + wv;
    if (i >= n) return;
    int h = lane >> 3;
    float mref = bf2f(mb[i * NH + h]);
    float inv = 1.f / (db[i * NH + h] + 1e-16f);
    int d0 = off[i], d1 = off[i + 1];
    float acc0 = 0.f, acc1 = 0.f;
    #pragma unroll 4
    for (int p = d0; p < d1; p++) {
        int sr = srp[p] & 0x0fffffff;
        float w = expf(atts[(size_t)p * NH + h] - mref) * inv;
        unsigned int u = *reinterpret_cast<const unsigned int*>(
            vt + (size_t)sr * ND + lane * 2);
        acc0 += w * bf2f(u & 0xffff);
        acc1 += w * bf2f(u >> 16);
    }
    float2 o; o.x = acc0; o.y = acc1;
    *reinterpret_cast<float2*>(aggr + (size_t)i * ND + lane * 2) = o;
}

// ================= FALLBACK PATH (round-3 proven kernels) =================

__global__ void k_proj(int n, const float* x_in, const int* ntype, const int* order,
                       const float* Kw, const float* Kb,
                       const float* Qw, const float* Qb,
                       const float* Vw, const float* Vb,
                       ushort_t* kn, ushort_t* qn, ushort_t* vn, ushort_t* v1) {
    __shared__ float xs[NB][ND];
    __shared__ int nodes[NB];
    __shared__ int types[NB];
    int tid = threadIdx.x;
    int base = blockIdx.x * NB;
    int cnt = min(NB, n - base);
    if (tid < cnt) { int nd = order[base + tid]; nodes[tid] = nd; types[tid] = ntype[nd]; }
    __syncthreads();
    for (int j = 0; j < cnt; j++) xs[j][tid] = x_in[(size_t)nodes[j] * ND + tid];
    __syncthreads();
    bool uni = (types[0] == types[cnt - 1]);
    for (int m = 0; m < 4; m++) {
        const float *W, *B; ushort_t* out; int forced_t = -1;
        if (m == 0)      { W = Kw; B = Kb; out = kn; }
        else if (m == 1) { W = Qw; B = Qb; out = qn; }
        else if (m == 2) { W = Vw; B = Vb; out = vn; }
        else             { W = Vw; B = Vb; out = v1; forced_t = 1; }
        if (uni || forced_t >= 0) {
            int t = (forced_t >= 0) ? forced_t : types[0];
            float bias = B[t * ND + tid];
            float acc[NB];
            #pragma unroll
            for (int j = 0; j < NB; j++) acc[j] = bias;
            const float* Wp = W + (size_t)t * ND * ND + tid;
            for (int d = 0; d < ND; d++) {
                float w = Wp[(size_t)d * ND];
                #pragma unroll
                for (int j = 0; j < NB; j++) acc[j] += xs[j][d] * w;
            }
            for (int j = 0; j < cnt; j++) out[(size_t)nodes[j] * ND + tid] = f2bf(acc[j]);
        } else {
            for (int j = 0; j < cnt; j++) {
                int t = types[j];
                float acc = B[t * ND + tid];
                const float* Wp = W + (size_t)t * ND * ND + tid;
                for (int d = 0; d < ND; d++) acc += xs[j][d] * Wp[(size_t)d * ND];
                out[(size_t)nodes[j] * ND + tid] = f2bf(acc);
            }
        }
    }
}

__global__ void k_att(int e, const int* src, const int* tgt, const int* etype, const int* ntype,
                      const ushort_t* kn, const ushort_t* qn,
                      const float* r_att, const float* r_pri, float* att) {
    int id = blockIdx.x * 256 + threadIdx.x;
    if (id >= e * NH) return;
    int ee = id >> 3, h = id & 7;
    int s = src[ee], t = tgt[ee], r = etype[ee];
    float kf[16], qf[16];
    load_bf8(kn + (size_t)s * ND + h * DKK, kf);
    load_bf8(kn + (size_t)s * ND + h * DKK + 8, kf + 8);
    load_bf8(qn + (size_t)t * ND + h * DKK, qf);
    load_bf8(qn + (size_t)t * ND + h * DKK + 8, qf + 8);
    const float* W = r_att + (size_t)(r * NH + h) * DKK * DKK;
    float kt[16];
    #pragma unroll
    for (int f = 0; f < 16; f++) kt[f] = 0.f;
    #pragma unroll 4
    for (int d = 0; d < 16; d++) {
        float kd = kf[d];
        #pragma unroll
        for (int f = 0; f < 16; f++) kt[f] += kd * W[d * 16 + f];
    }
    float a = 0.f;
    #pragma unroll
    for (int f = 0; f < 16; f++) a += qf[f] * kt[f];
    int tt = ntype[t], st = ntype[s];
    float pri = r_pri[((tt * NR + r) * NT + st) * NH + h];
    float logit = a * pri * 0.25f;
    logit = fminf(fmaxf(logit, -1.0e4f), 1.0e4f);
    att[(size_t)ee * NH + h] = logit;
}

__global__ void k_mden(int n, const int* off, const int* sorted,
                       const float* att, ushort_t* mb, float* db) {
    int id = blockIdx.x * 256 + threadIdx.x;
    if (id >= n * NH) return;
    int i = id >> 3, h = id & 7;
    int d0 = off[i], d1 = off[i + 1];
    float m = -3.0e38f;
    for (int p = d0; p < d1; p++) m = fmaxf(m, att[(size_t)sorted[p] * NH + h]);
    ushort_t mh = (d1 > d0) ? f2bf(m) : (ushort_t)0;
    float mref = bf2f(mh);
    float den = 0.f;
    for (int p = d0; p < d1; p++) den += expf(att[(size_t)sorted[p] * NH + h] - mref);
    mb[id] = mh;
    db[id] = den;
}

__global__ void k_norm(int e, const int* tgt, const ushort_t* mb, const float* db, float* att) {
    int id = blockIdx.x * 256 + threadIdx.x;
    if (id >= e * NH) return;
    int ee = id >> 3, h = id & 7;
    int t = tgt[ee];
    float w = expf(att[id] - bf2f(mb[t * NH + h])) / (db[t * NH + h] + 1e-16f);
    att[id] = w;
}

__global__ void k_aggr(int n, const int* off, const int* sorted, const int* src, const int* etype,
                       const ushort_t* vn, const float* r_msg, const float* att, float* aggr) {
    int wv = threadIdx.x >> 6, lane = threadIdx.x & 63;
    int i = blockIdx.x * 4 + wv;
    if (i >= n) return;
    int h = lane >> 3, f0 = (lane & 7) * 2;
    int d0 = off[i], d1 = off[i + 1];
    float acc0 = 0.f, acc1 = 0.f;
    for (int p = d0; p < d1; p++) {
        int ee = sorted[p];
        int s = src[ee], r = etype[ee];
        float w = att[(size_t)ee * NH + h];
        float vj[16];
        load_bf8(vn + (size_t)s * ND + h * DKK, vj);
        load_bf8(vn + (size_t)s * ND + h * DKK + 8, vj + 8);
        const float* Wm = r_msg + (size_t)(r * NH + h) * DKK * DKK + f0;
        float a0 = 0.f, a1 = 0.f;
        #pragma unroll
        for (int d = 0; d < 16; d++) {
            a0 += vj[d] * Wm[d * 16];
            a1 += vj[d] * Wm[d * 16 + 1];
        }
        acc0 += w * a0; acc1 += w * a1;
    }
    aggr[(size_t)i * ND + h * DKK + f0]     = acc0;
    aggr[(size_t)i * ND + h * DKK + f0 + 1] = acc1;
}

// ---------------- shared epilogue ----------------

__global__ void k_spk(int n, const int* winner, const int* tgt, const ushort_t* v1,
                      const float* s2u, float* aggr) {
    __shared__ float xs[NB][ND];
    __shared__ int wn[NB];
    int tid = threadIdx.x;
    int base = blockIdx.x * NB;
    int cnt = min(NB, n - base);
    if (tid < cnt) wn[tid] = winner[base + tid];
    __syncthreads();
    for (int j = 0; j < cnt; j++) {
        int w = wn[j];
        xs[j][tid] = (w >= 0) ? bf2f(v1[(size_t)tgt[w] * ND + tid]) : 0.f;
    }
    __syncthreads();
    float acc[NB];
    #pragma unroll
    for (int j = 0; j < NB; j++) acc[j] = 0.f;
    const float* Wp = s2u + tid;
    for (int d = 0; d < ND; d++) {
        float w = Wp[(size_t)d * ND];
        #pragma unroll
        for (int j = 0; j < NB; j++) acc[j] += xs[j][d] * w;
    }
    for (int j = 0; j < cnt; j++) {
        size_t idx = (size_t)(base + j) * ND + tid;
        float g = aggr[idx] + acc[j];
        g = 0.5f * g * (1.f + erff(g * 0.70710678118f));
        aggr[idx] = g;
    }
}

__global__ void k_final(int n, const float* x_in, const int* ntype, const int* order,
                        const float* Aw, const float* Ab, const float* skip,
                        const float* aggr, float* out) {
    __shared__ float xs[NB][ND];
    __shared__ int nodes[NB];
    __shared__ int types[NB];
    int tid = threadIdx.x;
    int base = blockIdx.x * NB;
    int cnt = min(NB, n - base);
    if (tid < cnt) { int nd = order[base + tid]; nodes[tid] = nd; types[tid] = ntype[nd]; }
    __syncthreads();
    for (int j = 0; j < cnt; j++) xs[j][tid] = aggr[(size_t)nodes[j] * ND + tid];
    __syncthreads();
    bool uni = (types[0] == types[cnt - 1]);
    if (uni) {
        int t = types[0];
        float bias = Ab[t * ND + tid];
        float acc[NB];
        #pragma unroll
        for (int j = 0; j < NB; j++) acc[j] = bias;
        const float* Wp = Aw + (size_t)t * ND * ND + tid;
        for (int d = 0; d < ND; d++) {
            float w = Wp[(size_t)d * ND];
            #pragma unroll
            for (int j = 0; j < NB; j++) acc[j] += xs[j][d] * w;
        }
        float alpha = 1.f / (1.f + expf(-skip[t]));
        for (int j = 0; j < cnt; j++) {
            float xin = x_in[(size_t)nodes[j] * ND + tid];
            out[(size_t)nodes[j] * ND + tid] = acc[j] * alpha + xin * (1.f - alpha);
        }
    } else {
        for (int j = 0; j < cnt; j++) {
            int t = types[j];
            float acc = Ab[t * ND + tid];
            const float* Wp = Aw + (size_t)t * ND * ND + tid;
            for (int d = 0; d < ND; d++) acc += xs[j][d] * Wp[(size_t)d * ND];
            float alpha = 1.f / (1.f + expf(-skip[t]));
            float xin = x_in[(size_t)nodes[j] * ND + tid];
            out[(size_t)nodes[j] * ND + tid] = acc * alpha + xin * (1.f - alpha);
        }
    }
}

extern "C" void kernel_launch(void* const* d_in, const int* in_sizes, int n_in,
                              void* d_out, int out_size, void* d_ws, size_t ws_size,
                              hipStream_t stream) {
    const float* node_inp = (const float*)d_in[0];
    const int* node_type  = (const int*)d_in[1];
    const int* edge_index = (const int*)d_in[2];
    const int* edge_type  = (const int*)d_in[3];
    const float* Kw = (const float*)d_in[5];
    const float* Kb = (const float*)d_in[6];
    const float* Qw = (const float*)d_in[7];
    const float* Qb = (const float*)d_in[8];
    const float* Vw = (const float*)d_in[9];
    const float* Vb = (const float*)d_in[10];
    const float* Aw = (const float*)d_in[11];
    const float* Ab = (const float*)d_in[12];
    const float* r_pri = (const float*)d_in[13];
    const float* r_att = (const float*)d_in[14];
    const float* r_msg = (const float*)d_in[15];
    const float* s2u   = (const float*)d_in[16];
    const float* skip  = (const float*)d_in[17];

    int n = in_sizes[1];
    int e = in_sizes[3];
    const int* srcp = edge_index;
    const int* tgtp = edge_index + e;

    char* wsp = (char*)d_ws;
    size_t woff = 0;
    auto alloc = [&](size_t b) { void* p = wsp + woff; woff += (b + 255) & ~(size_t)255; return p; };

    // ---- common infra ----
    int* offs     = (int*)alloc((size_t)(n + 1) * 4);
    int* nxt      = (int*)alloc((size_t)n * 4);
    int* winner   = (int*)alloc((size_t)n * 4);
    int* order    = (int*)alloc((size_t)n * 4);
    int* tcnt     = (int*)alloc(16);
    int* tnext    = (int*)alloc(16);
    int* tstart   = (int*)alloc(16);
    int* bsum     = (int*)alloc(4096);
    int* boff     = (int*)alloc(4096);
    int* eord     = (int*)alloc((size_t)e * 4);   // fast: srp record; fallback: sorted edge id
    ushort_t* mb  = (ushort_t*)alloc((size_t)n * NH * 2);
    float* db     = (float*)alloc((size_t)n * NH * 4);
    ushort_t* v1b = (ushort_t*)alloc((size_t)n * ND * 2);
    float* att    = (float*)alloc((size_t)e * NH * 4);
    size_t commonEnd = woff;

    // ---- fast-path extra layout ----
    ushort_t* Kcomb = (ushort_t*)alloc((size_t)NT * NR * ND * ND * 2);
    ushort_t* Vcomb = (ushort_t*)alloc((size_t)NT * NR * ND * ND * 2);
    float* kbc      = (float*)alloc((size_t)NT * NR * ND * 4);
    float* vbc      = (float*)alloc((size_t)NT * NR * ND * 4);
    ushort_t* Wall  = (ushort_t*)alloc((size_t)NT * NMAT * 8 * 4 * 512 * 2);
    float* bcat     = (float*)alloc((size_t)NT * NMAT * ND * 4);
    char* F         = (char*)alloc((size_t)n * 1536);   // phase1: qn+kt; phase2: vt+aggr
    size_t fastEnd = woff;

    int gn = (n + 255) / 256;
    int ge = (e + 255) / 256;
    int nbscan = n / SCB + 1;
    int fast = (ws_size >= fastEnd) ? 1 : 0;

    k_zero<<<gn, 256, 0, stream>>>(n, offs, winner, tcnt);
    k_count<<<ge, 256, 0, stream>>>(n, e, srcp, tgtp, edge_type, node_type, offs, winner, tcnt);
    k_scanA<<<nbscan, 256, 0, stream>>>(n, offs, bsum);
    k_scanB<<<1, 64, 0, stream>>>(nbscan, bsum, boff, tcnt, tnext, tstart);
    k_scanC<<<nbscan, 256, 0, stream>>>(n, offs, nxt, boff);
    k_scatter<<<ge, 256, 0, stream>>>(n, e, srcp, tgtp, edge_type, node_type, nxt,
                                      eord, fast, tnext, order);

    if (fast) {
        // ======== FAST PATH ========
        ushort_t* qn  = (ushort_t*)F;
        ushort_t* kt  = (ushort_t*)(F + (size_t)n * 256);
        ushort_t* vt  = (ushort_t*)F;                         // overlays qn+kt (dead after k_attmd)
        float* aggr   = (float*)(F + (size_t)n * 1024);       // overlays kt tail (dead)
        int gproj = (n + 31) / 32 + NT;                       // upper bound on padded tiles

        k_comb<<<2 * NT * NR, 128, 0, stream>>>(Kw, Kb, r_att, Vw, Vb, r_msg,
                                                Kcomb, kbc, Vcomb, vbc);
        k_pack<<<NT * NMAT * 8 * 4, 64, 0, stream>>>(Qw, Qb, Vw, Vb, Kcomb, kbc,
                                                     Vcomb, vbc, Wall, bcat);
        // phase1: mats 0..5 -> qn, kt, v1b
        k_projm<<<gproj, 256, 0, stream>>>(n, node_inp, order, tcnt, tstart, Wall, bcat,
                                           0, 6, qn, kt, v1b, (ushort_t*)nullptr);
        // fused logits + online softmax (8 edges/iteration, sorted-order logits)
        k_attmd<<<(n + 3) / 4, 256, 0, stream>>>(n, offs, eord, node_type,
                                                 qn, kt, r_pri, att, mb, db);
        // phase2: mats 6..9 -> vt (overlays qn/kt)
        k_projm<<<gproj, 256, 0, stream>>>(n, node_inp, order, tcnt, tstart, Wall, bcat,
                                           6, 4, (ushort_t*)nullptr, (ushort_t*)nullptr,
                                           (ushort_t*)nullptr, vt);
        k_aggr_fast<<<(n + 3) / 4, 256, 0, stream>>>(n, offs, eord, vt, att, mb, db, aggr);
        k_spk<<<(n + NB - 1) / NB, 128, 0, stream>>>(n, winner, tgtp, v1b, s2u, aggr);
        k_final<<<(n + NB - 1) / NB, 128, 0, stream>>>(n, node_inp, node_type, order,
                                                       Aw, Ab, skip, aggr, (float*)d_out);
    } else {
        // ======== FALLBACK (round-3 layout, proven) ========
        woff = commonEnd;
        ushort_t* vn  = (ushort_t*)alloc((size_t)n * ND * 2);
        char* regA    = (char*)alloc((size_t)n * ND * 2 * 2);
        ushort_t* kn  = (ushort_t*)regA;
        ushort_t* qn  = (ushort_t*)(regA + (size_t)n * ND * 2);
        float* aggr   = (float*)regA;

        k_proj<<<(n + NB - 1) / NB, 128, 0, stream>>>(n, node_inp, node_type, order,
                                                      Kw, Kb, Qw, Qb, Vw, Vb, kn, qn, vn, v1b);
        k_att<<<(e * NH + 255) / 256, 256, 0, stream>>>(e, srcp, tgtp, edge_type, node_type,
                                                        kn, qn, r_att, r_pri, att);
        k_mden<<<(n * NH + 255) / 256, 256, 0, stream>>>(n, offs, eord, att, mb, db);
        k_norm<<<(e * NH + 255) / 256, 256, 0, stream>>>(e, tgtp, mb, db, att);
        k_aggr<<<(n + 3) / 4, 256, 0, stream>>>(n, offs, eord, srcp, edge_type, vn, r_msg, att, aggr);
        k_spk<<<(n + NB - 1) / NB, 128, 0, stream>>>(n, winner, tgtp, v1b, s2u, aggr);
        k_final<<<(n + NB - 1) / NB, 128, 0, stream>>>(n, node_inp, node_type, order,
                                                       Aw, Ab, skip, aggr, (float*)d_out);
    }
}

// Round 11
// 423.834 us; speedup vs baseline: 1.5850x; 1.1163x over previous
//
#include <hip/hip_runtime.h>
#include <hip/hip_bf16.h>
#include <math.h>

#define ND 128
#define NH 8
#define DKK 16
#define NT 3
#define NR 4
#define NB 8
#define NMAT 10   // packed mats: 0=Q, 1..4=K@att[r], 5=V(type1), 6..9=V@msg[r]
#define SCB 4096  // scan elems per block (256 threads x 16)

typedef unsigned short ushort_t;
typedef __bf16 bf16_t;
typedef bf16_t bf16x8 __attribute__((ext_vector_type(8)));
typedef float f32x4 __attribute__((ext_vector_type(4)));

__device__ __forceinline__ float bf2f(unsigned short u) {
    union { unsigned int i; float f; } v; v.i = ((unsigned int)u) << 16; return v.f;
}
__device__ __forceinline__ unsigned short f2bf(float f) {
    union { float f; unsigned int i; } v; v.f = f;
    unsigned int x = v.i;
    unsigned int lsb = (x >> 16) & 1u;
    x += 0x7fffu + lsb;
    return (unsigned short)(x >> 16);
}
__device__ __forceinline__ unsigned int pk2(float a, float b) {
    return (unsigned int)f2bf(a) | ((unsigned int)f2bf(b) << 16);
}
__device__ __forceinline__ void load_bf8(const ushort_t* p, float* o) {
    uint4 u = *reinterpret_cast<const uint4*>(p);
    o[0]=bf2f(u.x & 0xffff); o[1]=bf2f(u.x >> 16);
    o[2]=bf2f(u.y & 0xffff); o[3]=bf2f(u.y >> 16);
    o[4]=bf2f(u.z & 0xffff); o[5]=bf2f(u.z >> 16);
    o[6]=bf2f(u.w & 0xffff); o[7]=bf2f(u.w >> 16);
}
__device__ __forceinline__ bf16x8 as_bf16x8(uint4 u) {
    union { uint4 u; bf16x8 v; } c; c.u = u; return c.v;
}

// ---------------- sort / bucket infrastructure ----------------

__global__ void k_zero(int n, int* offs, int* winner, int* tcnt) {
    int i = blockIdx.x * 256 + threadIdx.x;
    if (i < n) { offs[i] = 0; winner[i] = -1; }
    if (i < NT) tcnt[i] = 0;
}

// wave-aggregated 3-bin atomics
__global__ void k_count(int n, int e, const int* src, const int* tgt, const int* etype,
                        const int* ntype, int* offs, int* winner, int* tcnt) {
    int i = blockIdx.x * 256 + threadIdx.x;
    if (i < e) {
        atomicAdd(&offs[tgt[i]], 1);
        if (etype[i] == 0) atomicMax(&winner[src[i]], i);  // numpy last-write-wins == max edge id
    }
    if (i < n) {
        int t = ntype[i];
        int lane = threadIdx.x & 63;
        #pragma unroll
        for (int tt = 0; tt < NT; tt++) {
            bool me = (t == tt);
            unsigned long long m = __ballot(me);
            if (me) {
                int lower = __popcll(m & ((1ull << lane) - 1ull));
                if (lower == 0) atomicAdd(&tcnt[tt], __popcll(m));
            }
        }
    }
}

// ---- multi-block exclusive scan (3 phases, each tiny) ----

__global__ void k_scanA(int n, const int* offs, int* bsum) {
    __shared__ int red[256];
    int b = blockIdx.x, tid = threadIdx.x;
    int base = b * SCB + tid * 16;
    int s = 0;
    #pragma unroll
    for (int i = 0; i < 16; i++) {
        int idx = base + i;
        if (idx < n) s += offs[idx];
    }
    red[tid] = s;
    __syncthreads();
    for (int d = 128; d > 0; d >>= 1) {
        if (tid < d) red[tid] += red[tid + d];
        __syncthreads();
    }
    if (tid == 0) bsum[b] = red[0];
}

__global__ void k_scanB(int nb, const int* bsum, int* boff,
                        const int* tcnt, int* tnext, int* tstart) {
    if (threadIdx.x == 0) {
        int run = 0;
        for (int b = 0; b < nb; b++) { boff[b] = run; run += bsum[b]; }
        int t0 = 0;
        for (int t = 0; t < NT; t++) { tnext[t] = t0; tstart[t] = t0; t0 += tcnt[t]; }
    }
}

__global__ void k_scanC(int n, int* offs, int* next, const int* boff) {
    __shared__ int red[256];
    int b = blockIdx.x, tid = threadIdx.x;
    int base = b * SCB + tid * 16;
    int v[16];
    int s = 0;
    #pragma unroll
    for (int i = 0; i < 16; i++) {
        int idx = base + i;
        v[i] = (idx < n) ? offs[idx] : 0;
        s += v[i];
    }
    red[tid] = s;
    __syncthreads();
    for (int d = 1; d < 256; d <<= 1) {
        int vv = (tid >= d) ? red[tid - d] : 0;
        __syncthreads();
        red[tid] += vv;
        __syncthreads();
    }
    int run = boff[b] + red[tid] - s;   // exclusive prefix for this thread
    #pragma unroll
    for (int i = 0; i < 16; i++) {
        int idx = base + i;
        if (idx < n) { offs[idx] = run; next[idx] = run; run += v[i]; }
    }
    if (base <= n && n < base + 16) offs[n] = run;   // grand total
}

// mode=1 (fast): eord[p] = (src*NR+etype) | ntype[src]<<28 ; mode=0: eord[p] = edge id
__global__ void k_scatter(int n, int e, const int* src, const int* tgt, const int* etype,
                          const int* ntype, int* next, int* eord, int mode,
                          int* tnext, int* order) {
    int i = blockIdx.x * 256 + threadIdx.x;
    if (i < e) {
        int p = atomicAdd(&next[tgt[i]], 1);
        if (mode) {
            int s = src[i];
            eord[p] = (s * NR + etype[i]) | (ntype[s] << 28);
        } else {
            eord[p] = i;
        }
    }
    if (i < n) {
        int t = ntype[i];
        int lane = threadIdx.x & 63;
        #pragma unroll
        for (int tt = 0; tt < NT; tt++) {
            bool me = (t == tt);
            unsigned long long m = __ballot(me);
            if (me) {
                int lower = __popcll(m & ((1ull << lane) - 1ull));
                int leader = __ffsll((long long)m) - 1;
                int base = 0;
                if (lane == leader) base = atomicAdd(&tnext[tt], __popcll(m));
                base = __shfl(base, leader, 64);
                order[base + lower] = i;
            }
        }
    }
}

// ================= FAST PATH =================

// Fused combine+pack: Wall in MFMA B-fragment order + folded biases, straight
// from Qw/Kw/Vw and the relation matrices (no intermediate, no barriers).
// blk = ((t*NMAT+m)*8+c)*4+kb ; n-col nn = c*16+(lane&15) -> h = c (block-uniform),
// f = lane&15 ; k = kb*32 + (lane>>4)*8 + j.
__global__ void k_pack(const float* Qw, const float* Qb, const float* Kw, const float* Kb,
                       const float* Vw, const float* Vb,
                       const float* r_att, const float* r_msg,
                       ushort_t* Wall, float* bcat) {
    int blk = blockIdx.x;
    int kb = blk & 3;
    int c = (blk >> 2) & 7;
    int tm = blk >> 5;
    int m = tm % NMAT, t = tm / NMAT;
    int lane = threadIdx.x;
    int nn = c * 16 + (lane & 15);
    int quad = lane >> 4;
    int k0 = kb * 32 + quad * 8;
    ushort_t* dst = Wall + (size_t)blk * 512 + lane * 8;

    if (m == 0 || m == 5) {
        const float* W = (m == 0) ? (Qw + (size_t)t * ND * ND) : (Vw + (size_t)ND * ND);
        const float* B = (m == 0) ? (Qb + t * ND) : (Vb + ND);
        #pragma unroll
        for (int j = 0; j < 8; j++) dst[j] = f2bf(W[(size_t)(k0 + j) * ND + nn]);
        if (kb == 0 && quad == 0) bcat[(t * NMAT + m) * ND + nn] = B[nn];
    } else {
        int r = (m <= 4) ? (m - 1) : (m - 6);
        const float* W0 = (m <= 4) ? Kw : Vw;
        const float* B0 = (m <= 4) ? Kb : Vb;
        const float* Wr = (m <= 4) ? r_att : r_msg;
        int h = c, f = lane & 15;
        float wcol[16];
        #pragma unroll
        for (int jj = 0; jj < 16; jj++)
            wcol[jj] = Wr[(((size_t)r * NH + h) * DKK + jj) * DKK + f];
        #pragma unroll
        for (int j = 0; j < 8; j++) {
            const float* row = W0 + ((size_t)t * ND + (k0 + j)) * ND + h * DKK;
            float s = 0.f;
            #pragma unroll
            for (int jj = 0; jj < 16; jj++) s += row[jj] * wcol[jj];
            dst[j] = f2bf(s);
        }
        if (kb == 0 && quad == 0) {
            const float* brow = B0 + t * ND + h * DKK;
            float sb = 0.f;
            #pragma unroll
            for (int jj = 0; jj < 16; jj++) sb += brow[jj] * wcol[jj];
            bcat[(t * NMAT + m) * ND + nn] = sb;
        }
    }
}

// MFMA projection: every block is type-uniform by construction (padded type segments)
__global__ void __launch_bounds__(256) k_projm(
    int n, const float* x_in, const int* order,
    const int* tcnt, const int* tstart,
    const ushort_t* Wall, const float* bcat,
    int m0, int nm,
    ushort_t* out_qn, ushort_t* out_kt, ushort_t* out_v1, ushort_t* out_vt)
{
    __shared__ __align__(16) ushort_t xs[4096];  // A-fragment-permuted bf16: [rt][kb][lane][8]
    __shared__ int nodes[32];
    // block -> (type, local tile)
    int b = blockIdx.x;
    int nb0 = (tcnt[0] + 31) >> 5, nb1 = (tcnt[1] + 31) >> 5, nb2 = (tcnt[2] + 31) >> 5;
    int t, lb;
    if (b < nb0)                  { t = 0; lb = b; }
    else if (b < nb0 + nb1)       { t = 1; lb = b - nb0; }
    else if (b < nb0 + nb1 + nb2) { t = 2; lb = b - nb0 - nb1; }
    else return;
    int segoff = lb * 32;
    int cnt = min(32, tcnt[t] - segoff);
    int segbase = tstart[t] + segoff;
    int tid = threadIdx.x;
    if (tid < 32) nodes[tid] = (tid < cnt) ? order[segbase + tid] : -1;
    __syncthreads();
    // stage x -> permuted bf16, two contiguous 16B writes per thread (conflict-free)
    {
        int row = tid >> 3;
        int d0 = (tid & 7) * 16;
        int rt = row >> 4, rl = row & 15;
        int kb = d0 >> 5, q0 = (d0 >> 3) & 3;
        uint4 c0, c1;
        if (row < cnt) {
            const float4* xp4 = (const float4*)(x_in + (size_t)nodes[row] * ND + d0);
            float4 a = xp4[0], b2 = xp4[1], c2 = xp4[2], d4 = xp4[3];
            c0.x = pk2(a.x, a.y);   c0.y = pk2(a.z, a.w);
            c0.z = pk2(b2.x, b2.y); c0.w = pk2(b2.z, b2.w);
            c1.x = pk2(c2.x, c2.y); c1.y = pk2(c2.z, c2.w);
            c1.z = pk2(d4.x, d4.y); c1.w = pk2(d4.z, d4.w);
        } else {
            c0.x = c0.y = c0.z = c0.w = 0u;
            c1 = c0;
        }
        *(uint4*)&xs[((rt * 4 + kb) * 64 + q0 * 16 + rl) * 8]       = c0;
        *(uint4*)&xs[((rt * 4 + kb) * 64 + (q0 + 1) * 16 + rl) * 8] = c1;
    }
    __syncthreads();

    int w = tid >> 6, lane = tid & 63;
    int rt = w & 1;                      // wave's row-tile (16 nodes)
    bf16x8 afr[4];
    #pragma unroll
    for (int kb = 0; kb < 4; kb++)
        afr[kb] = as_bf16x8(*(const uint4*)&xs[((rt * 4 + kb) * 64 + lane) * 8]);
    int nct = nm * 8;
    for (int ct = (w >> 1); ct < nct; ct += 2) {
        int m = m0 + (ct >> 3), c = ct & 7;
        const uint4* bp = (const uint4*)(Wall + ((((size_t)t * NMAT + m) * 8 + c) * 4) * 512);
        f32x4 acc = {0.f, 0.f, 0.f, 0.f};
        #pragma unroll
        for (int kb = 0; kb < 4; kb++) {
            bf16x8 bfr = as_bf16x8(bp[kb * 64 + lane]);
            acc = __builtin_amdgcn_mfma_f32_16x16x32_bf16(afr[kb], bfr, acc, 0, 0, 0);
        }
        int col = c * 16 + (lane & 15);
        float bias = bcat[(t * NMAT + m) * ND + col];
        int rbase = rt * 16 + (lane >> 4) * 4;
        #pragma unroll
        for (int r = 0; r < 4; r++) {
            int grow = rbase + r;
            if (grow >= cnt) continue;
            int node = nodes[grow];
            ushort_t val = f2bf(acc[r] + bias);
            if (m == 0)       out_qn[(size_t)node * ND + col] = val;
            else if (m <= 4)  out_kt[((size_t)node * NR + (m - 1)) * ND + col] = val;
            else if (m == 5)  out_v1[(size_t)node * ND + col] = val;
            else              out_vt[((size_t)node * NR + (m - 6)) * ND + col] = val;
        }
    }
}

// Fused logits + online segment softmax, wave per target node.
// lane = (edge-slot, head): 8 edges per iteration, no per-edge shuffles.
__global__ void __launch_bounds__(256) k_attmd(
    int n, const int* off, const int* srp, const int* ntype,
    const ushort_t* qn, const ushort_t* kt, const float* r_pri,
    float* atts, ushort_t* mb, float* db)
{
    int wv = threadIdx.x >> 6, lane = threadIdx.x & 63;
    int i = blockIdx.x * 4 + wv;
    if (i >= n) return;
    int h = lane & 7, slot = lane >> 3;
    int tt = ntype[i];
    float qf[16];
    load_bf8(qn + (size_t)i * ND + h * DKK, qf);
    load_bf8(qn + (size_t)i * ND + h * DKK + 8, qf + 8);
    const float* prib = r_pri + (size_t)(tt * NR * NT) * NH + h;
    int d0 = off[i], d1 = off[i + 1];
    float m = -3.0e38f, den = 0.f;
    #pragma unroll 2
    for (int p0 = d0; p0 < d1; p0 += 8) {
        int p = p0 + slot;
        bool live = (p < d1);
        int sp = live ? srp[p] : 0;
        int sr = sp & 0x0fffffff;            // src*NR + r
        int st = ((unsigned int)sp) >> 28;   // ntype[src]
        int r = sr & (NR - 1);
        float kf[16];
        const ushort_t* kp = kt + (size_t)sr * ND + h * DKK;
        load_bf8(kp, kf);
        load_bf8(kp + 8, kf + 8);
        float a = 0.f;
        #pragma unroll
        for (int f = 0; f < 16; f++) a += qf[f] * kf[f];
        float pri = prib[(r * NT + st) * NH];
        float logit = fminf(fmaxf(a * pri * 0.25f, -1.0e4f), 1.0e4f);  // NaN scrub
        if (live) {
            atts[(size_t)p * NH + h] = logit;                           // coalesced 256B
            float mnew = fmaxf(m, logit);
            den = den * expf(m - mnew) + expf(logit - mnew);
            m = mnew;
        }
    }
    // combine the 8 edge-slot partials per head (xor 8,16,32)
    #pragma unroll
    for (int d = 8; d < 64; d <<= 1) {
        float mo = __shfl_xor(m, d, 64);
        float dn = __shfl_xor(den, d, 64);
        float mnew = fmaxf(m, mo);
        den = den * expf(m - mnew) + dn * expf(mo - mnew);
        m = mnew;
    }
    if (slot == 0) {
        ushort_t mh = (d1 > d0) ? f2bf(m) : (ushort_t)0;
        float dfin = (d1 > d0) ? den * expf(m - bf2f(mh)) : 0.f;
        mb[i * NH + h] = mh;
        db[i * NH + h] = dfin;
    }
}

// wave-per-node aggregation; softmax normalize folded in; srp+atts read sequentially
__global__ void __launch_bounds__(256) k_aggr_fast(
    int n, const int* off, const int* srp, const ushort_t* vt, const float* atts,
    const ushort_t* mb, const float* db, float* aggr)
{
    int wv = threadIdx.x >> 6, lane = threadIdx.x & 63;
    int i = blockIdx.x * 4 + wv;
    if (i >= n) return;
    int h = lane >> 3;
    float mref = bf2f(mb[i * NH + h]);
    float inv = 1.f / (db[i * NH + h] + 1e-16f);
    int d0 = off[i], d1 = off[i + 1];
    float acc0 = 0.f, acc1 = 0.f;
    #pragma unroll 4
    for (int p = d0; p < d1; p++) {
        int sr = srp[p] & 0x0fffffff;
        float w = expf(atts[(size_t)p * NH + h] - mref) * inv;
        unsigned int u = *reinterpret_cast<const unsigned int*>(
            vt + (size_t)sr * ND + lane * 2);
        acc0 += w * bf2f(u & 0xffff);
        acc1 += w * bf2f(u >> 16);
    }
    float2 o; o.x = acc0; o.y = acc1;
    *reinterpret_cast<float2*>(aggr + (size_t)i * ND + lane * 2) = o;
}

// ================= FALLBACK PATH (round-3 proven kernels) =================

__global__ void k_proj(int n, const float* x_in, const int* ntype, const int* order,
                       const float* Kw, const float* Kb,
                       const float* Qw, const float* Qb,
                       const float* Vw, const float* Vb,
                       ushort_t* kn, ushort_t* qn, ushort_t* vn, ushort_t* v1) {
    __shared__ float xs[NB][ND];
    __shared__ int nodes[NB];
    __shared__ int types[NB];
    int tid = threadIdx.x;
    int base = blockIdx.x * NB;
    int cnt = min(NB, n - base);
    if (tid < cnt) { int nd = order[base + tid]; nodes[tid] = nd; types[tid] = ntype[nd]; }
    __syncthreads();
    for (int j = 0; j < cnt; j++) xs[j][tid] = x_in[(size_t)nodes[j] * ND + tid];
    __syncthreads();
    bool uni = (types[0] == types[cnt - 1]);
    for (int m = 0; m < 4; m++) {
        const float *W, *B; ushort_t* out; int forced_t = -1;
        if (m == 0)      { W = Kw; B = Kb; out = kn; }
        else if (m == 1) { W = Qw; B = Qb; out = qn; }
        else if (m == 2) { W = Vw; B = Vb; out = vn; }
        else             { W = Vw; B = Vb; out = v1; forced_t = 1; }
        if (uni || forced_t >= 0) {
            int t = (forced_t >= 0) ? forced_t : types[0];
            float bias = B[t * ND + tid];
            float acc[NB];
            #pragma unroll
            for (int j = 0; j < NB; j++) acc[j] = bias;
            const float* Wp = W + (size_t)t * ND * ND + tid;
            for (int d = 0; d < ND; d++) {
                float w = Wp[(size_t)d * ND];
                #pragma unroll
                for (int j = 0; j < NB; j++) acc[j] += xs[j][d] * w;
            }
            for (int j = 0; j < cnt; j++) out[(size_t)nodes[j] * ND + tid] = f2bf(acc[j]);
        } else {
            for (int j = 0; j < cnt; j++) {
                int t = types[j];
                float acc = B[t * ND + tid];
                const float* Wp = W + (size_t)t * ND * ND + tid;
                for (int d = 0; d < ND; d++) acc += xs[j][d] * Wp[(size_t)d * ND];
                out[(size_t)nodes[j] * ND + tid] = f2bf(acc);
            }
        }
    }
}

__global__ void k_att(int e, const int* src, const int* tgt, const int* etype, const int* ntype,
                      const ushort_t* kn, const ushort_t* qn,
                      const float* r_att, const float* r_pri, float* att) {
    int id = blockIdx.x * 256 + threadIdx.x;
    if (id >= e * NH) return;
    int ee = id >> 3, h = id & 7;
    int s = src[ee], t = tgt[ee], r = etype[ee];
    float kf[16], qf[16];
    load_bf8(kn + (size_t)s * ND + h * DKK, kf);
    load_bf8(kn + (size_t)s * ND + h * DKK + 8, kf + 8);
    load_bf8(qn + (size_t)t * ND + h * DKK, qf);
    load_bf8(qn + (size_t)t * ND + h * DKK + 8, qf + 8);
    const float* W = r_att + (size_t)(r * NH + h) * DKK * DKK;
    float kt[16];
    #pragma unroll
    for (int f = 0; f < 16; f++) kt[f] = 0.f;
    #pragma unroll 4
    for (int d = 0; d < 16; d++) {
        float kd = kf[d];
        #pragma unroll
        for (int f = 0; f < 16; f++) kt[f] += kd * W[d * 16 + f];
    }
    float a = 0.f;
    #pragma unroll
    for (int f = 0; f < 16; f++) a += qf[f] * kt[f];
    int tt = ntype[t], st = ntype[s];
    float pri = r_pri[((tt * NR + r) * NT + st) * NH + h];
    float logit = a * pri * 0.25f;
    logit = fminf(fmaxf(logit, -1.0e4f), 1.0e4f);
    att[(size_t)ee * NH + h] = logit;
}

__global__ void k_mden(int n, const int* off, const int* sorted,
                       const float* att, ushort_t* mb, float* db) {
    int id = blockIdx.x * 256 + threadIdx.x;
    if (id >= n * NH) return;
    int i = id >> 3, h = id & 7;
    int d0 = off[i], d1 = off[i + 1];
    float m = -3.0e38f;
    for (int p = d0; p < d1; p++) m = fmaxf(m, att[(size_t)sorted[p] * NH + h]);
    ushort_t mh = (d1 > d0) ? f2bf(m) : (ushort_t)0;
    float mref = bf2f(mh);
    float den = 0.f;
    for (int p = d0; p < d1; p++) den += expf(att[(size_t)sorted[p] * NH + h] - mref);
    mb[id] = mh;
    db[id] = den;
}

__global__ void k_norm(int e, const int* tgt, const ushort_t* mb, const float* db, float* att) {
    int id = blockIdx.x * 256 + threadIdx.x;
    if (id >= e * NH) return;
    int ee = id >> 3, h = id & 7;
    int t = tgt[ee];
    float w = expf(att[id] - bf2f(mb[t * NH + h])) / (db[t * NH + h] + 1e-16f);
    att[id] = w;
}

__global__ void k_aggr(int n, const int* off, const int* sorted, const int* src, const int* etype,
                       const ushort_t* vn, const float* r_msg, const float* att, float* aggr) {
    int wv = threadIdx.x >> 6, lane = threadIdx.x & 63;
    int i = blockIdx.x * 4 + wv;
    if (i >= n) return;
    int h = lane >> 3, f0 = (lane & 7) * 2;
    int d0 = off[i], d1 = off[i + 1];
    float acc0 = 0.f, acc1 = 0.f;
    for (int p = d0; p < d1; p++) {
        int ee = sorted[p];
        int s = src[ee], r = etype[ee];
        float w = att[(size_t)ee * NH + h];
        float vj[16];
        load_bf8(vn + (size_t)s * ND + h * DKK, vj);
        load_bf8(vn + (size_t)s * ND + h * DKK + 8, vj + 8);
        const float* Wm = r_msg + (size_t)(r * NH + h) * DKK * DKK + f0;
        float a0 = 0.f, a1 = 0.f;
        #pragma unroll
        for (int d = 0; d < 16; d++) {
            a0 += vj[d] * Wm[d * 16];
            a1 += vj[d] * Wm[d * 16 + 1];
        }
        acc0 += w * a0; acc1 += w * a1;
    }
    aggr[(size_t)i * ND + h * DKK + f0]     = acc0;
    aggr[(size_t)i * ND + h * DKK + f0 + 1] = acc1;
}

// ---------------- shared epilogue ----------------

__global__ void k_spk(int n, const int* winner, const int* tgt, const ushort_t* v1,
                      const float* s2u, float* aggr) {
    __shared__ float xs[NB][ND];
    __shared__ int wn[NB];
    int tid = threadIdx.x;
    int base = blockIdx.x * NB;
    int cnt = min(NB, n - base);
    if (tid < cnt) wn[tid] = winner[base + tid];
    __syncthreads();
    for (int j = 0; j < cnt; j++) {
        int w = wn[j];
        xs[j][tid] = (w >= 0) ? bf2f(v1[(size_t)tgt[w] * ND + tid]) : 0.f;
    }
    __syncthreads();
    float acc[NB];
    #pragma unroll
    for (int j = 0; j < NB; j++) acc[j] = 0.f;
    const float* Wp = s2u + tid;
    for (int d = 0; d < ND; d++) {
        float w = Wp[(size_t)d * ND];
        #pragma unroll
        for (int j = 0; j < NB; j++) acc[j] += xs[j][d] * w;
    }
    for (int j = 0; j < cnt; j++) {
        size_t idx = (size_t)(base + j) * ND + tid;
        float g = aggr[idx] + acc[j];
        g = 0.5f * g * (1.f + erff(g * 0.70710678118f));
        aggr[idx] = g;
    }
}

__global__ void k_final(int n, const float* x_in, const int* ntype, const int* order,
                        const float* Aw, const float* Ab, const float* skip,
                        const float* aggr, float* out) {
    __shared__ float xs[NB][ND];
    __shared__ int nodes[NB];
    __shared__ int types[NB];
    int tid = threadIdx.x;
    int base = blockIdx.x * NB;
    int cnt = min(NB, n - base);
    if (tid < cnt) { int nd = order[base + tid]; nodes[tid] = nd; types[tid] = ntype[nd]; }
    __syncthreads();
    for (int j = 0; j < cnt; j++) xs[j][tid] = aggr[(size_t)nodes[j] * ND + tid];
    __syncthreads();
    bool uni = (types[0] == types[cnt - 1]);
    if (uni) {
        int t = types[0];
        float bias = Ab[t * ND + tid];
        float acc[NB];
        #pragma unroll
        for (int j = 0; j < NB; j++) acc[j] = bias;
        const float* Wp = Aw + (size_t)t * ND * ND + tid;
        for (int d = 0; d < ND; d++) {
            float w = Wp[(size_t)d * ND];
            #pragma unroll
            for (int j = 0; j < NB; j++) acc[j] += xs[j][d] * w;
        }
        float alpha = 1.f / (1.f + expf(-skip[t]));
        for (int j = 0; j < cnt; j++) {
            float xin = x_in[(size_t)nodes[j] * ND + tid];
            out[(size_t)nodes[j] * ND + tid] = acc[j] * alpha + xin * (1.f - alpha);
        }
    } else {
        for (int j = 0; j < cnt; j++) {
            int t = types[j];
            float acc = Ab[t * ND + tid];
            const float* Wp = Aw + (size_t)t * ND * ND + tid;
            for (int d = 0; d < ND; d++) acc += xs[j][d] * Wp[(size_t)d * ND];
            float alpha = 1.f / (1.f + expf(-skip[t]));
            float xin = x_in[(size_t)nodes[j] * ND + tid];
            out[(size_t)nodes[j] * ND + tid] = acc * alpha + xin * (1.f - alpha);
        }
    }
}

extern "C" void kernel_launch(void* const* d_in, const int* in_sizes, int n_in,
                              void* d_out, int out_size, void* d_ws, size_t ws_size,
                              hipStream_t stream) {
    const float* node_inp = (const float*)d_in[0];
    const int* node_type  = (const int*)d_in[1];
    const int* edge_index = (const int*)d_in[2];
    const int* edge_type  = (const int*)d_in[3];
    const float* Kw = (const float*)d_in[5];
    const float* Kb = (const float*)d_in[6];
    const float* Qw = (const float*)d_in[7];
    const float* Qb = (const float*)d_in[8];
    const float* Vw = (const float*)d_in[9];
    const float* Vb = (const float*)d_in[10];
    const float* Aw = (const float*)d_in[11];
    const float* Ab = (const float*)d_in[12];
    const float* r_pri = (const float*)d_in[13];
    const float* r_att = (const float*)d_in[14];
    const float* r_msg = (const float*)d_in[15];
    const float* s2u   = (const float*)d_in[16];
    const float* skip  = (const float*)d_in[17];

    int n = in_sizes[1];
    int e = in_sizes[3];
    const int* srcp = edge_index;
    const int* tgtp = edge_index + e;

    char* wsp = (char*)d_ws;
    size_t woff = 0;
    auto alloc = [&](size_t b) { void* p = wsp + woff; woff += (b + 255) & ~(size_t)255; return p; };

    // ---- common infra ----
    int* offs     = (int*)alloc((size_t)(n + 1) * 4);
    int* nxt      = (int*)alloc((size_t)n * 4);
    int* winner   = (int*)alloc((size_t)n * 4);
    int* order    = (int*)alloc((size_t)n * 4);
    int* tcnt     = (int*)alloc(16);
    int* tnext    = (int*)alloc(16);
    int* tstart   = (int*)alloc(16);
    int* bsum     = (int*)alloc(4096);
    int* boff     = (int*)alloc(4096);
    int* eord     = (int*)alloc((size_t)e * 4);   // fast: srp record; fallback: sorted edge id
    ushort_t* mb  = (ushort_t*)alloc((size_t)n * NH * 2);
    float* db     = (float*)alloc((size_t)n * NH * 4);
    ushort_t* v1b = (ushort_t*)alloc((size_t)n * ND * 2);
    float* att    = (float*)alloc((size_t)e * NH * 4);
    size_t commonEnd = woff;

    // ---- fast-path extra layout ----
    ushort_t* Wall  = (ushort_t*)alloc((size_t)NT * NMAT * 8 * 4 * 512 * 2);
    float* bcat     = (float*)alloc((size_t)NT * NMAT * ND * 4);
    char* F         = (char*)alloc((size_t)n * 1536);   // phase1: qn+kt; phase2: vt+aggr
    size_t fastEnd = woff;

    int gn = (n + 255) / 256;
    int ge = (e + 255) / 256;
    int nbscan = n / SCB + 1;
    int fast = (ws_size >= fastEnd) ? 1 : 0;

    k_zero<<<gn, 256, 0, stream>>>(n, offs, winner, tcnt);
    k_count<<<ge, 256, 0, stream>>>(n, e, srcp, tgtp, edge_type, node_type, offs, winner, tcnt);
    k_scanA<<<nbscan, 256, 0, stream>>>(n, offs, bsum);
    k_scanB<<<1, 64, 0, stream>>>(nbscan, bsum, boff, tcnt, tnext, tstart);
    k_scanC<<<nbscan, 256, 0, stream>>>(n, offs, nxt, boff);
    k_scatter<<<ge, 256, 0, stream>>>(n, e, srcp, tgtp, edge_type, node_type, nxt,
                                      eord, fast, tnext, order);

    if (fast) {
        // ======== FAST PATH ========
        ushort_t* qn  = (ushort_t*)F;
        ushort_t* kt  = (ushort_t*)(F + (size_t)n * 256);
        ushort_t* vt  = (ushort_t*)F;                         // overlays qn+kt (dead after k_attmd)
        float* aggr   = (float*)(F + (size_t)n * 1024);       // overlays kt tail (dead)
        int gproj = (n + 31) / 32 + NT;                       // upper bound on padded tiles

        // fused combine+pack (no k_comb, no barriers)
        k_pack<<<NT * NMAT * 8 * 4, 64, 0, stream>>>(Qw, Qb, Kw, Kb, Vw, Vb,
                                                     r_att, r_msg, Wall, bcat);
        // phase1: mats 0..5 -> qn, kt, v1b
        k_projm<<<gproj, 256, 0, stream>>>(n, node_inp, order, tcnt, tstart, Wall, bcat,
                                           0, 6, qn, kt, v1b, (ushort_t*)nullptr);
        // fused logits + online softmax (8 edges/iteration, sorted-order logits)
        k_attmd<<<(n + 3) / 4, 256, 0, stream>>>(n, offs, eord, node_type,
                                                 qn, kt, r_pri, att, mb, db);
        // phase2: mats 6..9 -> vt (overlays qn/kt)
        k_projm<<<gproj, 256, 0, stream>>>(n, node_inp, order, tcnt, tstart, Wall, bcat,
                                           6, 4, (ushort_t*)nullptr, (ushort_t*)nullptr,
                                           (ushort_t*)nullptr, vt);
        k_aggr_fast<<<(n + 3) / 4, 256, 0, stream>>>(n, offs, eord, vt, att, mb, db, aggr);
        k_spk<<<(n + NB - 1) / NB, 128, 0, stream>>>(n, winner, tgtp, v1b, s2u, aggr);
        k_final<<<(n + NB - 1) / NB, 128, 0, stream>>>(n, node_inp, node_type, order,
                                                       Aw, Ab, skip, aggr, (float*)d_out);
    } else {
        // ======== FALLBACK (round-3 layout, proven) ========
        woff = commonEnd;
        ushort_t* vn  = (ushort_t*)alloc((size_t)n * ND * 2);
        char* regA    = (char*)alloc((size_t)n * ND * 2 * 2);
        ushort_t* kn  = (ushort_t*)regA;
        ushort_t* qn  = (ushort_t*)(regA + (size_t)n * ND * 2);
        float* aggr   = (float*)regA;

        k_proj<<<(n + NB - 1) / NB, 128, 0, stream>>>(n, node_inp, node_type, order,
                                                      Kw, Kb, Qw, Qb, Vw, Vb, kn, qn, vn, v1b);
        k_att<<<(e * NH + 255) / 256, 256, 0, stream>>>(e, srcp, tgtp, edge_type, node_type,
                                                        kn, qn, r_att, r_pri, att);
        k_mden<<<(n * NH + 255) / 256, 256, 0, stream>>>(n, offs, eord, att, mb, db);
        k_norm<<<(e * NH + 255) / 256, 256, 0, stream>>>(e, tgtp, mb, db, att);
        k_aggr<<<(n + 3) / 4, 256, 0, stream>>>(n, offs, eord, srcp, edge_type, vn, r_msg, att, aggr);
        k_spk<<<(n + NB - 1) / NB, 128, 0, stream>>>(n, winner, tgtp, v1b, s2u, aggr);
        k_final<<<(n + NB - 1) / NB, 128, 0, stream>>>(n, node_inp, node_type, order,
                                                       Aw, Ab, skip, aggr, (float*)d_out);
    }
}

// Round 12
// 371.166 us; speedup vs baseline: 1.8100x; 1.1419x over previous
//
#include <hip/hip_runtime.h>
#include <hip/hip_bf16.h>
#include <math.h>

#define ND 128
#define NH 8
#define DKK 16
#define NT 3
#define NR 4
#define NB 8
#define NMAT 12   // packed mats: 0=Q, 1..4=K@att[r], 5=V(type1), 6..9=V@msg[r], 10=A, 11=s2u
#define SCB 4096  // scan elems per block (256 threads x 16)

typedef unsigned short ushort_t;
typedef __bf16 bf16_t;
typedef bf16_t bf16x8 __attribute__((ext_vector_type(8)));
typedef float f32x4 __attribute__((ext_vector_type(4)));

__device__ __forceinline__ float bf2f(unsigned short u) {
    union { unsigned int i; float f; } v; v.i = ((unsigned int)u) << 16; return v.f;
}
__device__ __forceinline__ unsigned short f2bf(float f) {
    union { float f; unsigned int i; } v; v.f = f;
    unsigned int x = v.i;
    unsigned int lsb = (x >> 16) & 1u;
    x += 0x7fffu + lsb;
    return (unsigned short)(x >> 16);
}
__device__ __forceinline__ unsigned int pk2(float a, float b) {
    return (unsigned int)f2bf(a) | ((unsigned int)f2bf(b) << 16);
}
__device__ __forceinline__ void load_bf8(const ushort_t* p, float* o) {
    uint4 u = *reinterpret_cast<const uint4*>(p);
    o[0]=bf2f(u.x & 0xffff); o[1]=bf2f(u.x >> 16);
    o[2]=bf2f(u.y & 0xffff); o[3]=bf2f(u.y >> 16);
    o[4]=bf2f(u.z & 0xffff); o[5]=bf2f(u.z >> 16);
    o[6]=bf2f(u.w & 0xffff); o[7]=bf2f(u.w >> 16);
}
__device__ __forceinline__ bf16x8 as_bf16x8(uint4 u) {
    union { uint4 u; bf16x8 v; } c; c.u = u; return c.v;
}

// ---------------- sort / bucket infrastructure ----------------

__global__ void k_zero(int n, int* offs, int* winner, int* tcnt) {
    int i = blockIdx.x * 256 + threadIdx.x;
    if (i < n) { offs[i] = 0; winner[i] = -1; }
    if (i < NT) tcnt[i] = 0;
}

// wave-aggregated 3-bin atomics
__global__ void k_count(int n, int e, const int* src, const int* tgt, const int* etype,
                        const int* ntype, int* offs, int* winner, int* tcnt) {
    int i = blockIdx.x * 256 + threadIdx.x;
    if (i < e) {
        atomicAdd(&offs[tgt[i]], 1);
        if (etype[i] == 0) atomicMax(&winner[src[i]], i);  // numpy last-write-wins == max edge id
    }
    if (i < n) {
        int t = ntype[i];
        int lane = threadIdx.x & 63;
        #pragma unroll
        for (int tt = 0; tt < NT; tt++) {
            bool me = (t == tt);
            unsigned long long m = __ballot(me);
            if (me) {
                int lower = __popcll(m & ((1ull << lane) - 1ull));
                if (lower == 0) atomicAdd(&tcnt[tt], __popcll(m));
            }
        }
    }
}

// ---- multi-block exclusive scan (3 phases, each tiny) ----

__global__ void k_scanA(int n, const int* offs, int* bsum) {
    __shared__ int red[256];
    int b = blockIdx.x, tid = threadIdx.x;
    int base = b * SCB + tid * 16;
    int s = 0;
    #pragma unroll
    for (int i = 0; i < 16; i++) {
        int idx = base + i;
        if (idx < n) s += offs[idx];
    }
    red[tid] = s;
    __syncthreads();
    for (int d = 128; d > 0; d >>= 1) {
        if (tid < d) red[tid] += red[tid + d];
        __syncthreads();
    }
    if (tid == 0) bsum[b] = red[0];
}

__global__ void k_scanB(int nb, const int* bsum, int* boff,
                        const int* tcnt, int* tnext, int* tstart) {
    if (threadIdx.x == 0) {
        int run = 0;
        for (int b = 0; b < nb; b++) { boff[b] = run; run += bsum[b]; }
        int t0 = 0;
        for (int t = 0; t < NT; t++) { tnext[t] = t0; tstart[t] = t0; t0 += tcnt[t]; }
    }
}

__global__ void k_scanC(int n, int* offs, int* next, const int* boff) {
    __shared__ int red[256];
    int b = blockIdx.x, tid = threadIdx.x;
    int base = b * SCB + tid * 16;
    int v[16];
    int s = 0;
    #pragma unroll
    for (int i = 0; i < 16; i++) {
        int idx = base + i;
        v[i] = (idx < n) ? offs[idx] : 0;
        s += v[i];
    }
    red[tid] = s;
    __syncthreads();
    for (int d = 1; d < 256; d <<= 1) {
        int vv = (tid >= d) ? red[tid - d] : 0;
        __syncthreads();
        red[tid] += vv;
        __syncthreads();
    }
    int run = boff[b] + red[tid] - s;   // exclusive prefix for this thread
    #pragma unroll
    for (int i = 0; i < 16; i++) {
        int idx = base + i;
        if (idx < n) { offs[idx] = run; next[idx] = run; run += v[i]; }
    }
    if (base <= n && n < base + 16) offs[n] = run;   // grand total
}

// mode=1 (fast): eord[p] = (src*NR+etype) | ntype[src]<<28 ; mode=0: eord[p] = edge id
__global__ void k_scatter(int n, int e, const int* src, const int* tgt, const int* etype,
                          const int* ntype, int* next, int* eord, int mode,
                          int* tnext, int* order) {
    int i = blockIdx.x * 256 + threadIdx.x;
    if (i < e) {
        int p = atomicAdd(&next[tgt[i]], 1);
        if (mode) {
            int s = src[i];
            eord[p] = (s * NR + etype[i]) | (ntype[s] << 28);
        } else {
            eord[p] = i;
        }
    }
    if (i < n) {
        int t = ntype[i];
        int lane = threadIdx.x & 63;
        #pragma unroll
        for (int tt = 0; tt < NT; tt++) {
            bool me = (t == tt);
            unsigned long long m = __ballot(me);
            if (me) {
                int lower = __popcll(m & ((1ull << lane) - 1ull));
                int leader = __ffsll((long long)m) - 1;
                int base = 0;
                if (lane == leader) base = atomicAdd(&tnext[tt], __popcll(m));
                base = __shfl(base, leader, 64);
                order[base + lower] = i;
            }
        }
    }
}

// ================= FAST PATH =================

// Fused combine+pack into MFMA B-fragment order + folded biases.
// blk = ((t*NMAT+m)*8+c)*4+kb ; nn = c*16+(lane&15) -> h = c (block-uniform),
// f = lane&15 ; k = kb*32 + (lane>>4)*8 + j.
__global__ void k_pack(const float* Qw, const float* Qb, const float* Kw, const float* Kb,
                       const float* Vw, const float* Vb, const float* Aw, const float* Ab,
                       const float* s2u, const float* r_att, const float* r_msg,
                       ushort_t* Wall, float* bcat) {
    int blk = blockIdx.x;
    int kb = blk & 3;
    int c = (blk >> 2) & 7;
    int tm = blk >> 5;
    int m = tm % NMAT, t = tm / NMAT;
    int lane = threadIdx.x;
    int nn = c * 16 + (lane & 15);
    int quad = lane >> 4;
    int k0 = kb * 32 + quad * 8;
    ushort_t* dst = Wall + (size_t)blk * 512 + lane * 8;

    if (m == 0 || m == 5 || m == 10 || m == 11) {
        const float* W; const float* B;
        if (m == 0)       { W = Qw + (size_t)t * ND * ND; B = Qb + t * ND; }
        else if (m == 5)  { W = Vw + (size_t)ND * ND;     B = Vb + ND; }
        else if (m == 10) { W = Aw + (size_t)t * ND * ND; B = Ab + t * ND; }
        else              { W = s2u;                      B = nullptr; }
        #pragma unroll
        for (int j = 0; j < 8; j++) dst[j] = f2bf(W[(size_t)(k0 + j) * ND + nn]);
        if (kb == 0 && quad == 0)
            bcat[(t * NMAT + m) * ND + nn] = B ? B[nn] : 0.f;
    } else {
        int r = (m <= 4) ? (m - 1) : (m - 6);
        const float* W0 = (m <= 4) ? Kw : Vw;
        const float* B0 = (m <= 4) ? Kb : Vb;
        const float* Wr = (m <= 4) ? r_att : r_msg;
        int h = c, f = lane & 15;
        float wcol[16];
        #pragma unroll
        for (int jj = 0; jj < 16; jj++)
            wcol[jj] = Wr[(((size_t)r * NH + h) * DKK + jj) * DKK + f];
        #pragma unroll
        for (int j = 0; j < 8; j++) {
            const float* row = W0 + ((size_t)t * ND + (k0 + j)) * ND + h * DKK;
            float s = 0.f;
            #pragma unroll
            for (int jj = 0; jj < 16; jj++) s += row[jj] * wcol[jj];
            dst[j] = f2bf(s);
        }
        if (kb == 0 && quad == 0) {
            const float* brow = B0 + t * ND + h * DKK;
            float sb = 0.f;
            #pragma unroll
            for (int jj = 0; jj < 16; jj++) sb += brow[jj] * wcol[jj];
            bcat[(t * NMAT + m) * ND + nn] = sb;
        }
    }
}

// MFMA projection: every block is type-uniform by construction (padded type segments)
__global__ void __launch_bounds__(256) k_projm(
    int n, const float* x_in, const int* order,
    const int* tcnt, const int* tstart,
    const ushort_t* Wall, const float* bcat,
    int m0, int nm,
    ushort_t* out_qn, ushort_t* out_kt, ushort_t* out_v1, ushort_t* out_vt)
{
    __shared__ __align__(16) ushort_t xs[4096];  // A-fragment-permuted bf16: [rt][kb][lane][8]
    __shared__ int nodes[32];
    int b = blockIdx.x;
    int nb0 = (tcnt[0] + 31) >> 5, nb1 = (tcnt[1] + 31) >> 5, nb2 = (tcnt[2] + 31) >> 5;
    int t, lb;
    if (b < nb0)                  { t = 0; lb = b; }
    else if (b < nb0 + nb1)       { t = 1; lb = b - nb0; }
    else if (b < nb0 + nb1 + nb2) { t = 2; lb = b - nb0 - nb1; }
    else return;
    int segoff = lb * 32;
    int cnt = min(32, tcnt[t] - segoff);
    int segbase = tstart[t] + segoff;
    int tid = threadIdx.x;
    if (tid < 32) nodes[tid] = (tid < cnt) ? order[segbase + tid] : -1;
    __syncthreads();
    {
        int row = tid >> 3;
        int d0 = (tid & 7) * 16;
        int rt = row >> 4, rl = row & 15;
        int kb = d0 >> 5, q0 = (d0 >> 3) & 3;
        uint4 c0, c1;
        if (row < cnt) {
            const float4* xp4 = (const float4*)(x_in + (size_t)nodes[row] * ND + d0);
            float4 a = xp4[0], b2 = xp4[1], c2 = xp4[2], d4 = xp4[3];
            c0.x = pk2(a.x, a.y);   c0.y = pk2(a.z, a.w);
            c0.z = pk2(b2.x, b2.y); c0.w = pk2(b2.z, b2.w);
            c1.x = pk2(c2.x, c2.y); c1.y = pk2(c2.z, c2.w);
            c1.z = pk2(d4.x, d4.y); c1.w = pk2(d4.z, d4.w);
        } else {
            c0.x = c0.y = c0.z = c0.w = 0u;
            c1 = c0;
        }
        *(uint4*)&xs[((rt * 4 + kb) * 64 + q0 * 16 + rl) * 8]       = c0;
        *(uint4*)&xs[((rt * 4 + kb) * 64 + (q0 + 1) * 16 + rl) * 8] = c1;
    }
    __syncthreads();

    int w = tid >> 6, lane = tid & 63;
    int rt = w & 1;
    bf16x8 afr[4];
    #pragma unroll
    for (int kb = 0; kb < 4; kb++)
        afr[kb] = as_bf16x8(*(const uint4*)&xs[((rt * 4 + kb) * 64 + lane) * 8]);
    int nct = nm * 8;
    for (int ct = (w >> 1); ct < nct; ct += 2) {
        int m = m0 + (ct >> 3), c = ct & 7;
        const uint4* bp = (const uint4*)(Wall + ((((size_t)t * NMAT + m) * 8 + c) * 4) * 512);
        f32x4 acc = {0.f, 0.f, 0.f, 0.f};
        #pragma unroll
        for (int kb = 0; kb < 4; kb++) {
            bf16x8 bfr = as_bf16x8(bp[kb * 64 + lane]);
            acc = __builtin_amdgcn_mfma_f32_16x16x32_bf16(afr[kb], bfr, acc, 0, 0, 0);
        }
        int col = c * 16 + (lane & 15);
        float bias = bcat[(t * NMAT + m) * ND + col];
        int rbase = rt * 16 + (lane >> 4) * 4;
        #pragma unroll
        for (int r = 0; r < 4; r++) {
            int grow = rbase + r;
            if (grow >= cnt) continue;
            int node = nodes[grow];
            ushort_t val = f2bf(acc[r] + bias);
            if (m == 0)       out_qn[(size_t)node * ND + col] = val;
            else if (m <= 4)  out_kt[((size_t)node * NR + (m - 1)) * ND + col] = val;
            else if (m == 5)  out_v1[(size_t)node * ND + col] = val;
            else              out_vt[((size_t)node * NR + (m - 6)) * ND + col] = val;
        }
    }
}

// MFMA speaker: aggr += gelu-input rows v1b[tgt[winner]] @ s2u, then exact GELU in-place
__global__ void __launch_bounds__(256) k_spkm(
    int n, const int* winner, const int* tgt, const ushort_t* v1b,
    const ushort_t* Wall, float* aggr)
{
    __shared__ __align__(16) ushort_t xs[4096];
    __shared__ int wsrc[32];
    int base = blockIdx.x * 32;
    int cnt = min(32, n - base);
    if (cnt <= 0) return;
    int tid = threadIdx.x;
    if (tid < 32) {
        int w = (tid < cnt) ? winner[base + tid] : -1;
        wsrc[tid] = (w >= 0) ? tgt[w] : -1;
    }
    __syncthreads();
    {
        int row = tid >> 3;
        int d0 = (tid & 7) * 16;
        int rt = row >> 4, rl = row & 15;
        int kb = d0 >> 5, q0 = (d0 >> 3) & 3;
        uint4 c0, c1;
        int s = (row < cnt) ? wsrc[row] : -1;
        if (s >= 0) {
            const uint4* vp = (const uint4*)(v1b + (size_t)s * ND + d0);
            c0 = vp[0]; c1 = vp[1];
        } else { c0.x = c0.y = c0.z = c0.w = 0u; c1 = c0; }
        *(uint4*)&xs[((rt * 4 + kb) * 64 + q0 * 16 + rl) * 8]       = c0;
        *(uint4*)&xs[((rt * 4 + kb) * 64 + (q0 + 1) * 16 + rl) * 8] = c1;
    }
    __syncthreads();

    int w = tid >> 6, lane = tid & 63;
    int rt = w & 1;
    bf16x8 afr[4];
    #pragma unroll
    for (int kb = 0; kb < 4; kb++)
        afr[kb] = as_bf16x8(*(const uint4*)&xs[((rt * 4 + kb) * 64 + lane) * 8]);
    for (int ct = (w >> 1); ct < 8; ct += 2) {
        const uint4* bp = (const uint4*)(Wall + (((size_t)11 * 8 + ct) * 4) * 512);  // t=0, m=11
        f32x4 acc = {0.f, 0.f, 0.f, 0.f};
        #pragma unroll
        for (int kb = 0; kb < 4; kb++) {
            bf16x8 bfr = as_bf16x8(bp[kb * 64 + lane]);
            acc = __builtin_amdgcn_mfma_f32_16x16x32_bf16(afr[kb], bfr, acc, 0, 0, 0);
        }
        int col = ct * 16 + (lane & 15);
        int rbase = rt * 16 + (lane >> 4) * 4;
        #pragma unroll
        for (int r = 0; r < 4; r++) {
            int grow = rbase + r;
            if (grow >= cnt) continue;
            size_t idx = (size_t)(base + grow) * ND + col;
            float g = aggr[idx] + acc[r];
            g = 0.5f * g * (1.f + erff(g * 0.70710678118f));
            aggr[idx] = g;
        }
    }
}

// MFMA final: out = (aggr @ Aw[t] + Ab[t]) * alpha + x_in * (1-alpha), type-uniform tiles
__global__ void __launch_bounds__(256) k_finalm(
    int n, const float* x_in, const int* order, const int* tcnt, const int* tstart,
    const ushort_t* Wall, const float* bcat, const float* skip,
    const float* aggr, float* out)
{
    __shared__ __align__(16) ushort_t xs[4096];
    __shared__ int nodes[32];
    int b = blockIdx.x;
    int nb0 = (tcnt[0] + 31) >> 5, nb1 = (tcnt[1] + 31) >> 5, nb2 = (tcnt[2] + 31) >> 5;
    int t, lb;
    if (b < nb0)                  { t = 0; lb = b; }
    else if (b < nb0 + nb1)       { t = 1; lb = b - nb0; }
    else if (b < nb0 + nb1 + nb2) { t = 2; lb = b - nb0 - nb1; }
    else return;
    int segoff = lb * 32;
    int cnt = min(32, tcnt[t] - segoff);
    int segbase = tstart[t] + segoff;
    int tid = threadIdx.x;
    if (tid < 32) nodes[tid] = (tid < cnt) ? order[segbase + tid] : -1;
    __syncthreads();
    {
        int row = tid >> 3;
        int d0 = (tid & 7) * 16;
        int rt = row >> 4, rl = row & 15;
        int kb = d0 >> 5, q0 = (d0 >> 3) & 3;
        uint4 c0, c1;
        if (row < cnt) {
            const float4* xp4 = (const float4*)(aggr + (size_t)nodes[row] * ND + d0);
            float4 a = xp4[0], b2 = xp4[1], c2 = xp4[2], d4 = xp4[3];
            c0.x = pk2(a.x, a.y);   c0.y = pk2(a.z, a.w);
            c0.z = pk2(b2.x, b2.y); c0.w = pk2(b2.z, b2.w);
            c1.x = pk2(c2.x, c2.y); c1.y = pk2(c2.z, c2.w);
            c1.z = pk2(d4.x, d4.y); c1.w = pk2(d4.z, d4.w);
        } else {
            c0.x = c0.y = c0.z = c0.w = 0u;
            c1 = c0;
        }
        *(uint4*)&xs[((rt * 4 + kb) * 64 + q0 * 16 + rl) * 8]       = c0;
        *(uint4*)&xs[((rt * 4 + kb) * 64 + (q0 + 1) * 16 + rl) * 8] = c1;
    }
    __syncthreads();

    float alpha = 1.f / (1.f + expf(-skip[t]));
    int w = tid >> 6, lane = tid & 63;
    int rt = w & 1;
    bf16x8 afr[4];
    #pragma unroll
    for (int kb = 0; kb < 4; kb++)
        afr[kb] = as_bf16x8(*(const uint4*)&xs[((rt * 4 + kb) * 64 + lane) * 8]);
    for (int ct = (w >> 1); ct < 8; ct += 2) {
        const uint4* bp = (const uint4*)(Wall + ((((size_t)t * NMAT + 10) * 8 + ct) * 4) * 512);
        f32x4 acc = {0.f, 0.f, 0.f, 0.f};
        #pragma unroll
        for (int kb = 0; kb < 4; kb++) {
            bf16x8 bfr = as_bf16x8(bp[kb * 64 + lane]);
            acc = __builtin_amdgcn_mfma_f32_16x16x32_bf16(afr[kb], bfr, acc, 0, 0, 0);
        }
        int col = ct * 16 + (lane & 15);
        float bias = bcat[(t * NMAT + 10) * ND + col];
        int rbase = rt * 16 + (lane >> 4) * 4;
        #pragma unroll
        for (int r = 0; r < 4; r++) {
            int grow = rbase + r;
            if (grow >= cnt) continue;
            int node = nodes[grow];
            float xin = x_in[(size_t)node * ND + col];
            out[(size_t)node * ND + col] = (acc[r] + bias) * alpha + xin * (1.f - alpha);
        }
    }
}

// Fused logits + online segment softmax, wave per target node.
__global__ void __launch_bounds__(256) k_attmd(
    int n, const int* off, const int* srp, const int* ntype,
    const ushort_t* qn, const ushort_t* kt, const float* r_pri,
    float* atts, ushort_t* mb, float* db)
{
    int wv = threadIdx.x >> 6, lane = threadIdx.x & 63;
    int i = blockIdx.x * 4 + wv;
    if (i >= n) return;
    int h = lane & 7, slot = lane >> 3;
    int tt = ntype[i];
    float qf[16];
    load_bf8(qn + (size_t)i * ND + h * DKK, qf);
    load_bf8(qn + (size_t)i * ND + h * DKK + 8, qf + 8);
    const float* prib = r_pri + (size_t)(tt * NR * NT) * NH + h;
    int d0 = off[i], d1 = off[i + 1];
    float m = -3.0e38f, den = 0.f;
    #pragma unroll 2
    for (int p0 = d0; p0 < d1; p0 += 8) {
        int p = p0 + slot;
        bool live = (p < d1);
        int sp = live ? srp[p] : 0;
        int sr = sp & 0x0fffffff;
        int st = ((unsigned int)sp) >> 28;
        int r = sr & (NR - 1);
        float kf[16];
        const ushort_t* kp = kt + (size_t)sr * ND + h * DKK;
        load_bf8(kp, kf);
        load_bf8(kp + 8, kf + 8);
        float a = 0.f;
        #pragma unroll
        for (int f = 0; f < 16; f++) a += qf[f] * kf[f];
        float pri = prib[(r * NT + st) * NH];
        float logit = fminf(fmaxf(a * pri * 0.25f, -1.0e4f), 1.0e4f);
        if (live) {
            atts[(size_t)p * NH + h] = logit;
            float mnew = fmaxf(m, logit);
            den = den * expf(m - mnew) + expf(logit - mnew);
            m = mnew;
        }
    }
    #pragma unroll
    for (int d = 8; d < 64; d <<= 1) {
        float mo = __shfl_xor(m, d, 64);
        float dn = __shfl_xor(den, d, 64);
        float mnew = fmaxf(m, mo);
        den = den * expf(m - mnew) + dn * expf(mo - mnew);
        m = mnew;
    }
    if (slot == 0) {
        ushort_t mh = (d1 > d0) ? f2bf(m) : (ushort_t)0;
        float dfin = (d1 > d0) ? den * expf(m - bf2f(mh)) : 0.f;
        mb[i * NH + h] = mh;
        db[i * NH + h] = dfin;
    }
}

// wave-per-node aggregation; softmax normalize folded in
__global__ void __launch_bounds__(256) k_aggr_fast(
    int n, const int* off, const int* srp, const ushort_t* vt, const float* atts,
    const ushort_t* mb, const float* db, float* aggr)
{
    int wv = threadIdx.x >> 6, lane = threadIdx.x & 63;
    int i = blockIdx.x * 4 + wv;
    if (i >= n) return;
    int h = lane >> 3;
    float mref = bf2f(mb[i * NH + h]);
    float inv = 1.f / (db[i * NH + h] + 1e-16f);
    int d0 = off[i], d1 = off[i + 1];
    float acc0 = 0.f, acc1 = 0.f;
    #pragma unroll 4
    for (int p = d0; p < d1; p++) {
        int sr = srp[p] & 0x0fffffff;
        float w = expf(atts[(size_t)p * NH + h] - mref) * inv;
        unsigned int u = *reinterpret_cast<const unsigned int*>(
            vt + (size_t)sr * ND + lane * 2);
        acc0 += w * bf2f(u & 0xffff);
        acc1 += w * bf2f(u >> 16);
    }
    float2 o; o.x = acc0; o.y = acc1;
    *reinterpret_cast<float2*>(aggr + (size_t)i * ND + lane * 2) = o;
}

// ================= FALLBACK PATH (round-3 proven kernels) =================

__global__ void k_proj(int n, const float* x_in, const int* ntype, const int* order,
                       const float* Kw, const float* Kb,
                       const float* Qw, const float* Qb,
                       const float* Vw, const float* Vb,
                       ushort_t* kn, ushort_t* qn, ushort_t* vn, ushort_t* v1) {
    __shared__ float xs[NB][ND];
    __shared__ int nodes[NB];
    __shared__ int types[NB];
    int tid = threadIdx.x;
    int base = blockIdx.x * NB;
    int cnt = min(NB, n - base);
    if (tid < cnt) { int nd = order[base + tid]; nodes[tid] = nd; types[tid] = ntype[nd]; }
    __syncthreads();
    for (int j = 0; j < cnt; j++) xs[j][tid] = x_in[(size_t)nodes[j] * ND + tid];
    __syncthreads();
    bool uni = (types[0] == types[cnt - 1]);
    for (int m = 0; m < 4; m++) {
        const float *W, *B; ushort_t* out; int forced_t = -1;
        if (m == 0)      { W = Kw; B = Kb; out = kn; }
        else if (m == 1) { W = Qw; B = Qb; out = qn; }
        else if (m == 2) { W = Vw; B = Vb; out = vn; }
        else             { W = Vw; B = Vb; out = v1; forced_t = 1; }
        if (uni || forced_t >= 0) {
            int t = (forced_t >= 0) ? forced_t : types[0];
            float bias = B[t * ND + tid];
            float acc[NB];
            #pragma unroll
            for (int j = 0; j < NB; j++) acc[j] = bias;
            const float* Wp = W + (size_t)t * ND * ND + tid;
            for (int d = 0; d < ND; d++) {
                float w = Wp[(size_t)d * ND];
                #pragma unroll
                for (int j = 0; j < NB; j++) acc[j] += xs[j][d] * w;
            }
            for (int j = 0; j < cnt; j++) out[(size_t)nodes[j] * ND + tid] = f2bf(acc[j]);
        } else {
            for (int j = 0; j < cnt; j++) {
                int t = types[j];
                float acc = B[t * ND + tid];
                const float* Wp = W + (size_t)t * ND * ND + tid;
                for (int d = 0; d < ND; d++) acc += xs[j][d] * Wp[(size_t)d * ND];
                out[(size_t)nodes[j] * ND + tid] = f2bf(acc);
            }
        }
    }
}

__global__ void k_att(int e, const int* src, const int* tgt, const int* etype, const int* ntype,
                      const ushort_t* kn, const ushort_t* qn,
                      const float* r_att, const float* r_pri, float* att) {
    int id = blockIdx.x * 256 + threadIdx.x;
    if (id >= e * NH) return;
    int ee = id >> 3, h = id & 7;
    int s = src[ee], t = tgt[ee], r = etype[ee];
    float kf[16], qf[16];
    load_bf8(kn + (size_t)s * ND + h * DKK, kf);
    load_bf8(kn + (size_t)s * ND + h * DKK + 8, kf + 8);
    load_bf8(qn + (size_t)t * ND + h * DKK, qf);
    load_bf8(qn + (size_t)t * ND + h * DKK + 8, qf + 8);
    const float* W = r_att + (size_t)(r * NH + h) * DKK * DKK;
    float kt[16];
    #pragma unroll
    for (int f = 0; f < 16; f++) kt[f] = 0.f;
    #pragma unroll 4
    for (int d = 0; d < 16; d++) {
        float kd = kf[d];
        #pragma unroll
        for (int f = 0; f < 16; f++) kt[f] += kd * W[d * 16 + f];
    }
    float a = 0.f;
    #pragma unroll
    for (int f = 0; f < 16; f++) a += qf[f] * kt[f];
    int tt = ntype[t], st = ntype[s];
    float pri = r_pri[((tt * NR + r) * NT + st) * NH + h];
    float logit = a * pri * 0.25f;
    logit = fminf(fmaxf(logit, -1.0e4f), 1.0e4f);
    att[(size_t)ee * NH + h] = logit;
}

__global__ void k_mden(int n, const int* off, const int* sorted,
                       const float* att, ushort_t* mb, float* db) {
    int id = blockIdx.x * 256 + threadIdx.x;
    if (id >= n * NH) return;
    int i = id >> 3, h = id & 7;
    int d0 = off[i], d1 = off[i + 1];
    float m = -3.0e38f;
    for (int p = d0; p < d1; p++) m = fmaxf(m, att[(size_t)sorted[p] * NH + h]);
    ushort_t mh = (d1 > d0) ? f2bf(m) : (ushort_t)0;
    float mref = bf2f(mh);
    float den = 0.f;
    for (int p = d0; p < d1; p++) den += expf(att[(size_t)sorted[p] * NH + h] - mref);
    mb[id] = mh;
    db[id] = den;
}

__global__ void k_norm(int e, const int* tgt, const ushort_t* mb, const float* db, float* att) {
    int id = blockIdx.x * 256 + threadIdx.x;
    if (id >= e * NH) return;
    int ee = id >> 3, h = id & 7;
    int t = tgt[ee];
    float w = expf(att[id] - bf2f(mb[t * NH + h])) / (db[t * NH + h] + 1e-16f);
    att[id] = w;
}

__global__ void k_aggr(int n, const int* off, const int* sorted, const int* src, const int* etype,
                       const ushort_t* vn, const float* r_msg, const float* att, float* aggr) {
    int wv = threadIdx.x >> 6, lane = threadIdx.x & 63;
    int i = blockIdx.x * 4 + wv;
    if (i >= n) return;
    int h = lane >> 3, f0 = (lane & 7) * 2;
    int d0 = off[i], d1 = off[i + 1];
    float acc0 = 0.f, acc1 = 0.f;
    for (int p = d0; p < d1; p++) {
        int ee = sorted[p];
        int s = src[ee], r = etype[ee];
        float w = att[(size_t)ee * NH + h];
        float vj[16];
        load_bf8(vn + (size_t)s * ND + h * DKK, vj);
        load_bf8(vn + (size_t)s * ND + h * DKK + 8, vj + 8);
        const float* Wm = r_msg + (size_t)(r * NH + h) * DKK * DKK + f0;
        float a0 = 0.f, a1 = 0.f;
        #pragma unroll
        for (int d = 0; d < 16; d++) {
            a0 += vj[d] * Wm[d * 16];
            a1 += vj[d] * Wm[d * 16 + 1];
        }
        acc0 += w * a0; acc1 += w * a1;
    }
    aggr[(size_t)i * ND + h * DKK + f0]     = acc0;
    aggr[(size_t)i * ND + h * DKK + f0 + 1] = acc1;
}

__global__ void k_spk(int n, const int* winner, const int* tgt, const ushort_t* v1,
                      const float* s2u, float* aggr) {
    __shared__ float xs[NB][ND];
    __shared__ int wn[NB];
    int tid = threadIdx.x;
    int base = blockIdx.x * NB;
    int cnt = min(NB, n - base);
    if (tid < cnt) wn[tid] = winner[base + tid];
    __syncthreads();
    for (int j = 0; j < cnt; j++) {
        int w = wn[j];
        xs[j][tid] = (w >= 0) ? bf2f(v1[(size_t)tgt[w] * ND + tid]) : 0.f;
    }
    __syncthreads();
    float acc[NB];
    #pragma unroll
    for (int j = 0; j < NB; j++) acc[j] = 0.f;
    const float* Wp = s2u + tid;
    for (int d = 0; d < ND; d++) {
        float w = Wp[(size_t)d * ND];
        #pragma unroll
        for (int j = 0; j < NB; j++) acc[j] += xs[j][d] * w;
    }
    for (int j = 0; j < cnt; j++) {
        size_t idx = (size_t)(base + j) * ND + tid;
        float g = aggr[idx] + acc[j];
        g = 0.5f * g * (1.f + erff(g * 0.70710678118f));
        aggr[idx] = g;
    }
}

__global__ void k_final(int n, const float* x_in, const int* ntype, const int* order,
                        const float* Aw, const float* Ab, const float* skip,
                        const float* aggr, float* out) {
    __shared__ float xs[NB][ND];
    __shared__ int nodes[NB];
    __shared__ int types[NB];
    int tid = threadIdx.x;
    int base = blockIdx.x * NB;
    int cnt = min(NB, n - base);
    if (tid < cnt) { int nd = order[base + tid]; nodes[tid] = nd; types[tid] = ntype[nd]; }
    __syncthreads();
    for (int j = 0; j < cnt; j++) xs[j][tid] = aggr[(size_t)nodes[j] * ND + tid];
    __syncthreads();
    bool uni = (types[0] == types[cnt - 1]);
    if (uni) {
        int t = types[0];
        float bias = Ab[t * ND + tid];
        float acc[NB];
        #pragma unroll
        for (int j = 0; j < NB; j++) acc[j] = bias;
        const float* Wp = Aw + (size_t)t * ND * ND + tid;
        for (int d = 0; d < ND; d++) {
            float w = Wp[(size_t)d * ND];
            #pragma unroll
            for (int j = 0; j < NB; j++) acc[j] += xs[j][d] * w;
        }
        float alpha = 1.f / (1.f + expf(-skip[t]));
        for (int j = 0; j < cnt; j++) {
            float xin = x_in[(size_t)nodes[j] * ND + tid];
            out[(size_t)nodes[j] * ND + tid] = acc[j] * alpha + xin * (1.f - alpha);
        }
    } else {
        for (int j = 0; j < cnt; j++) {
            int t = types[j];
            float acc = Ab[t * ND + tid];
            const float* Wp = Aw + (size_t)t * ND * ND + tid;
            for (int d = 0; d < ND; d++) acc += xs[j][d] * Wp[(size_t)d * ND];
            float alpha = 1.f / (1.f + expf(-skip[t]));
            float xin = x_in[(size_t)nodes[j] * ND + tid];
            out[(size_t)nodes[j] * ND + tid] = acc * alpha + xin * (1.f - alpha);
        }
    }
}

extern "C" void kernel_launch(void* const* d_in, const int* in_sizes, int n_in,
                              void* d_out, int out_size, void* d_ws, size_t ws_size,
                              hipStream_t stream) {
    const float* node_inp = (const float*)d_in[0];
    const int* node_type  = (const int*)d_in[1];
    const int* edge_index = (const int*)d_in[2];
    const int* edge_type  = (const int*)d_in[3];
    const float* Kw = (const float*)d_in[5];
    const float* Kb = (const float*)d_in[6];
    const float* Qw = (const float*)d_in[7];
    const float* Qb = (const float*)d_in[8];
    const float* Vw = (const float*)d_in[9];
    const float* Vb = (const float*)d_in[10];
    const float* Aw = (const float*)d_in[11];
    const float* Ab = (const float*)d_in[12];
    const float* r_pri = (const float*)d_in[13];
    const float* r_att = (const float*)d_in[14];
    const float* r_msg = (const float*)d_in[15];
    const float* s2u   = (const float*)d_in[16];
    const float* skip  = (const float*)d_in[17];

    int n = in_sizes[1];
    int e = in_sizes[3];
    const int* srcp = edge_index;
    const int* tgtp = edge_index + e;

    char* wsp = (char*)d_ws;
    size_t woff = 0;
    auto alloc = [&](size_t b) { void* p = wsp + woff; woff += (b + 255) & ~(size_t)255; return p; };

    // ---- common infra ----
    int* offs     = (int*)alloc((size_t)(n + 1) * 4);
    int* nxt      = (int*)alloc((size_t)n * 4);
    int* winner   = (int*)alloc((size_t)n * 4);
    int* order    = (int*)alloc((size_t)n * 4);
    int* tcnt     = (int*)alloc(16);
    int* tnext    = (int*)alloc(16);
    int* tstart   = (int*)alloc(16);
    int* bsum     = (int*)alloc(4096);
    int* boff     = (int*)alloc(4096);
    int* eord     = (int*)alloc((size_t)e * 4);   // fast: srp record; fallback: sorted edge id
    ushort_t* mb  = (ushort_t*)alloc((size_t)n * NH * 2);
    float* db     = (float*)alloc((size_t)n * NH * 4);
    ushort_t* v1b = (ushort_t*)alloc((size_t)n * ND * 2);
    float* att    = (float*)alloc((size_t)e * NH * 4);
    size_t commonEnd = woff;

    // ---- fast-path extra layout ----
    ushort_t* Wall  = (ushort_t*)alloc((size_t)NT * NMAT * 8 * 4 * 512 * 2);
    float* bcat     = (float*)alloc((size_t)NT * NMAT * ND * 4);
    char* F         = (char*)alloc((size_t)n * 1536);   // phase1: qn+kt; phase2: vt+aggr
    size_t fastEnd = woff;

    int gn = (n + 255) / 256;
    int ge = (e + 255) / 256;
    int nbscan = n / SCB + 1;
    int fast = (ws_size >= fastEnd) ? 1 : 0;

    k_zero<<<gn, 256, 0, stream>>>(n, offs, winner, tcnt);
    k_count<<<ge, 256, 0, stream>>>(n, e, srcp, tgtp, edge_type, node_type, offs, winner, tcnt);
    k_scanA<<<nbscan, 256, 0, stream>>>(n, offs, bsum);
    k_scanB<<<1, 64, 0, stream>>>(nbscan, bsum, boff, tcnt, tnext, tstart);
    k_scanC<<<nbscan, 256, 0, stream>>>(n, offs, nxt, boff);
    k_scatter<<<ge, 256, 0, stream>>>(n, e, srcp, tgtp, edge_type, node_type, nxt,
                                      eord, fast, tnext, order);

    if (fast) {
        // ======== FAST PATH ========
        ushort_t* qn  = (ushort_t*)F;
        ushort_t* kt  = (ushort_t*)(F + (size_t)n * 256);
        ushort_t* vt  = (ushort_t*)F;                         // overlays qn+kt (dead after k_attmd)
        float* aggr   = (float*)(F + (size_t)n * 1024);       // overlays kt tail (dead)
        int gproj = (n + 31) / 32 + NT;                       // upper bound on padded tiles

        k_pack<<<NT * NMAT * 8 * 4, 64, 0, stream>>>(Qw, Qb, Kw, Kb, Vw, Vb, Aw, Ab,
                                                     s2u, r_att, r_msg, Wall, bcat);
        // phase1: mats 0..5 -> qn, kt, v1b
        k_projm<<<gproj, 256, 0, stream>>>(n, node_inp, order, tcnt, tstart, Wall, bcat,
                                           0, 6, qn, kt, v1b, (ushort_t*)nullptr);
        k_attmd<<<(n + 3) / 4, 256, 0, stream>>>(n, offs, eord, node_type,
                                                 qn, kt, r_pri, att, mb, db);
        // phase2: mats 6..9 -> vt (overlays qn/kt)
        k_projm<<<gproj, 256, 0, stream>>>(n, node_inp, order, tcnt, tstart, Wall, bcat,
                                           6, 4, (ushort_t*)nullptr, (ushort_t*)nullptr,
                                           (ushort_t*)nullptr, vt);
        k_aggr_fast<<<(n + 3) / 4, 256, 0, stream>>>(n, offs, eord, vt, att, mb, db, aggr);
        // MFMA epilogue: speaker (s2u) + GELU, then A-projection + skip blend
        k_spkm<<<(n + 31) / 32, 256, 0, stream>>>(n, winner, tgtp, v1b, Wall, aggr);
        k_finalm<<<gproj, 256, 0, stream>>>(n, node_inp, order, tcnt, tstart, Wall, bcat,
                                            skip, aggr, (float*)d_out);
    } else {
        // ======== FALLBACK (round-3 layout, proven) ========
        woff = commonEnd;
        ushort_t* vn  = (ushort_t*)alloc((size_t)n * ND * 2);
        char* regA    = (char*)alloc((size_t)n * ND * 2 * 2);
        ushort_t* kn  = (ushort_t*)regA;
        ushort_t* qn  = (ushort_t*)(regA + (size_t)n * ND * 2);
        float* aggr   = (float*)regA;

        k_proj<<<(n + NB - 1) / NB, 128, 0, stream>>>(n, node_inp, node_type, order,
                                                      Kw, Kb, Qw, Qb, Vw, Vb, kn, qn, vn, v1b);
        k_att<<<(e * NH + 255) / 256, 256, 0, stream>>>(e, srcp, tgtp, edge_type, node_type,
                                                        kn, qn, r_att, r_pri, att);
        k_mden<<<(n * NH + 255) / 256, 256, 0, stream>>>(n, offs, eord, att, mb, db);
        k_norm<<<(e * NH + 255) / 256, 256, 0, stream>>>(e, tgtp, mb, db, att);
        k_aggr<<<(n + 3) / 4, 256, 0, stream>>>(n, offs, eord, srcp, edge_type, vn, r_msg, att, aggr);
        k_spk<<<(n + NB - 1) / NB, 128, 0, stream>>>(n, winner, tgtp, v1b, s2u, aggr);
        k_final<<<(n + NB - 1) / NB, 128, 0, stream>>>(n, node_inp, node_type, order,
                                                       Aw, Ab, skip, aggr, (float*)d_out);
    }
}